// Round 10
// baseline (856.074 us; speedup 1.0000x reference)
//
#include <hip/hip_runtime.h>
#include <hip/hip_bf16.h>

#define Bn 16
#define Nn 4096
#define Pn 1024
#define Sn 32
#define Cn 64
#define EPSn 1e-5f
#define ALPHAn 0.2f

// ---- fp32 weight table (fps scalar path; layouts identical to R9) ----
#define W1O 0       // [68][64] k-order [feat64|xyz3|pad]
#define W2O 4352    // [64][64]
#define W3O 8448    // [64][128]
#define AO  16640   // two col-halves [132][64]; k-order [h3|xyz|pad]
#define B1O 33536
#define B2O 33600
#define B3O 33664
#define WSF 33792
__device__ __align__(16) float g_W[WSF];

// ---- split-bf16 weights [N][Kpad], h and l planes (u16 units) ----
// W1b [64][96] (k>=67 zero), W2b [64][64], W3b [128][64], Ab [128][160] (k>=131 zero)
#define W1BH 0
#define W1BL 6144
#define W2BH 12288
#define W2BL 16384
#define W3BH 20480
#define W3BL 28672
#define ABH  36864
#define ABL  57344
#define WBU  77824
#define NPAIR 38912
__device__ __align__(16) unsigned short g_Wb[WBU];

typedef __attribute__((ext_vector_type(8))) short short8;
typedef __attribute__((ext_vector_type(4))) float f32x4;

__device__ __forceinline__ void split2(float v, unsigned short& hu, unsigned short& lu) {
  __hip_bfloat16 h = __float2bfloat16(v);
  float hv = __bfloat162float(h);
  __hip_bfloat16 l = __float2bfloat16(v - hv);
  hu = *(unsigned short*)&h;
  lu = *(unsigned short*)&l;
}
__device__ __forceinline__ float bf2f(unsigned short u) {
  __hip_bfloat16 h = *(__hip_bfloat16*)&u;
  return __bfloat162float(h);
}

__global__ void prep_kernel(
    const float* __restrict__ w1, const float* __restrict__ b1,
    const float* __restrict__ g1, const float* __restrict__ bt1,
    const float* __restrict__ m1, const float* __restrict__ v1,
    const float* __restrict__ w2, const float* __restrict__ b2,
    const float* __restrict__ g2, const float* __restrict__ bt2,
    const float* __restrict__ m2, const float* __restrict__ v2,
    const float* __restrict__ w3, const float* __restrict__ b3,
    const float* __restrict__ g3, const float* __restrict__ bt3,
    const float* __restrict__ m3, const float* __restrict__ v3,
    const float* __restrict__ a)
{
  const int idx = blockIdx.x * blockDim.x + threadIdx.x;
  if (idx < WSF) {
    float val;
    if (idx < W2O) {
      const int k = idx >> 6, o = idx & 63;
      const float sc = g1[o] * rsqrtf(v1[o] + EPSn);
      val = (k < 64) ? w1[o * 67 + 3 + k] * sc
          : (k < 67) ? w1[o * 67 + (k - 64)] * sc : 0.f;
    } else if (idx < W3O) {
      const int r = idx - W2O, k = r >> 6, o = r & 63;
      val = w2[o * 64 + k] * (g2[o] * rsqrtf(v2[o] + EPSn));
    } else if (idx < AO) {
      const int r = idx - W3O, k = r >> 7, o = r & 127;
      val = w3[o * 64 + k] * (g3[o] * rsqrtf(v3[o] + EPSn));
    } else if (idx < B1O) {
      int r = idx - AO;
      const int half = r / 8448; r -= half * 8448;
      const int k = r >> 6, o = half * 64 + (r & 63);
      val = (k < 128) ? a[(3 + k) * 128 + o]
          : (k < 131) ? a[(k - 128) * 128 + o] : 0.f;
    } else if (idx < B2O) {
      const int o = idx - B1O;
      val = (b1[o] - m1[o]) * (g1[o] * rsqrtf(v1[o] + EPSn)) + bt1[o];
    } else if (idx < B3O) {
      const int o = idx - B2O;
      val = (b2[o] - m2[o]) * (g2[o] * rsqrtf(v2[o] + EPSn)) + bt2[o];
    } else {
      const int o = idx - B3O;
      val = (b3[o] - m3[o]) * (g3[o] * rsqrtf(v3[o] + EPSn)) + bt3[o];
    }
    g_W[idx] = val;
  } else if (idx < WSF + NPAIR) {
    const int i = idx - WSF;
    float w; int ho, lo;
    if (i < 6144) {                       // W1b [64][96]
      const int n = i / 96, k = i % 96;
      const float s = g1[n] * rsqrtf(v1[n] + EPSn);
      w = (k < 64) ? w1[n * 67 + 3 + k] * s
        : (k < 67) ? w1[n * 67 + (k - 64)] * s : 0.f;
      ho = W1BH + i; lo = W1BL + i;
    } else if (i < 10240) {               // W2b [64][64]
      const int r = i - 6144, n = r >> 6, k = r & 63;
      w = w2[n * 64 + k] * (g2[n] * rsqrtf(v2[n] + EPSn));
      ho = W2BH + r; lo = W2BL + r;
    } else if (i < 18432) {               // W3b [128][64]
      const int r = i - 10240, n = r >> 6, k = r & 63;
      w = w3[n * 64 + k] * (g3[n] * rsqrtf(v3[n] + EPSn));
      ho = W3BH + r; lo = W3BL + r;
    } else {                              // Ab [128][160]
      const int r = i - 18432, n = r / 160, k = r % 160;
      w = (k < 128) ? a[(3 + k) * 128 + n]
        : (k < 131) ? a[(k - 128) * 128 + n] : 0.f;
      ho = ABH + r; lo = ABL + r;
    }
    unsigned short hu, lu; split2(w, hu, lu);
    g_Wb[ho] = hu; g_Wb[lo] = lu;
  }
}

// ---- LDS layout (bytes). 75312 B -> 2 blocks/CU ----
// XA: gather input bf16 h/l [64][80] (k-order feat|xyz|zeros); h2 reuses cols 0..63.
// XB: h1 bf16 h/l [64][64]; EQ (fp32 [64][33] softmax quarters) aliases after ph2.
// XH: [h3(128)|rxyz(3)|zeros] bf16 h/l [64][144].
// FS: fp32 small: newxyz[2][4]@0, FA[2][64]@8 (fpsfeat->F2), FB[2][128]@136 (F1->F3->EB).
#define SA 80
#define SB 64
#define SHX 144
#define OXAH 0
#define OXAL 10240
#define OXBH 20480
#define OXBL 28672
#define OXHH 36864
#define OXHL 55296
#define OEQ  20480
#define OFS  73728
#define OZST 75296
#define LDSB 75312

#define MFMA_BF16 __builtin_amdgcn_mfma_f32_16x16x32_bf16

__global__ __launch_bounds__(256) void fused_kernel(
    const float* __restrict__ xyz, const float* __restrict__ points,
    const int* __restrict__ fps_idx, const int* __restrict__ group_idx,
    float* __restrict__ out)
{
  __shared__ __align__(16) unsigned char LB[LDSB];
  unsigned short* XAh = (unsigned short*)(LB + OXAH);
  unsigned short* XAl = (unsigned short*)(LB + OXAL);
  unsigned short* XBh = (unsigned short*)(LB + OXBH);
  unsigned short* XBl = (unsigned short*)(LB + OXBL);
  unsigned short* XHh = (unsigned short*)(LB + OXHH);
  unsigned short* XHl = (unsigned short*)(LB + OXHL);
  float*          EQ  = (float*)(LB + OEQ);
  float*          FS  = (float*)(LB + OFS);
  unsigned short* ZS  = (unsigned short*)(LB + OZST);

  const int t = threadIdx.x, lane = t & 63, wave = t >> 6;
  const int quad = lane >> 4, nn = lane & 15;
  const int m0 = wave * 16;                  // row-tile base (rows 0-31 grp0, 32-63 grp1)
  const int tg = t >> 7, tq = t & 127;
  const int gg = blockIdx.x * 2 + tg;
  const int b_t = gg >> 10, p_t = gg & 1023;

  // ---- S0: zero stub; fps point; new_xyz; out0 ----
  if (t < 4) ((float*)ZS)[t] = 0.f;
  {
    const int fi = fps_idx[gg];
    if (tq < 64) {
      FS[8 + tg * 64 + tq] = points[b_t * Cn * Nn + tq * Nn + fi];
    } else if (tq < 67) {
      const int d = tq - 64;
      const float v = xyz[b_t * 3 * Nn + d * Nn + fi];
      FS[tg * 4 + d] = v;
      out[(b_t * 3 + d) * Pn + p_t] = v;
    }
  }
  __syncthreads();

  // ---- S1: gather -> XA (bf16 h/l) + rxyz -> XA[64..66], XH[128..130]; zero pads ----
  {
    const int s0 = tq >> 2, cg = tq & 3;
    const int row = tg * 32 + s0;
    const int gi = group_idx[gg * Sn + s0];
    const float* prow = points + b_t * Cn * Nn + gi;
    const int c0 = cg * 16;
    #pragma unroll
    for (int k = 0; k < 16; ++k) {
      unsigned short hu, lu; split2(prow[(c0 + k) * Nn], hu, lu);
      XAh[row * SA + c0 + k] = hu; XAl[row * SA + c0 + k] = lu;
    }
    if (cg == 0) {
      #pragma unroll
      for (int d = 0; d < 3; ++d) {
        const float r = xyz[b_t * 3 * Nn + d * Nn + gi] - FS[tg * 4 + d];
        unsigned short hu, lu; split2(r, hu, lu);
        XAh[row * SA + 64 + d] = hu; XAl[row * SA + 64 + d] = lu;
        XHh[row * SHX + 128 + d] = hu; XHl[row * SHX + 128 + d] = lu;
      }
    } else if (cg == 1) {
      #pragma unroll
      for (int j = 0; j < 13; ++j) { XAh[row * SA + 67 + j] = 0; XAl[row * SA + 67 + j] = 0; }
    } else if (cg == 2) {
      #pragma unroll
      for (int j = 0; j < 13; ++j) { XHh[row * SHX + 131 + j] = 0; XHl[row * SHX + 131 + j] = 0; }
    }
  }
  __syncthreads();

  f32x4 C[8];

  // ===== Phase 1: X(XA,K96) @ W1b -> h1(XB); fps-L1 =====
  #pragma unroll
  for (int i = 0; i < 4; ++i) C[i] = (f32x4){0.f, 0.f, 0.f, 0.f};
  #pragma unroll
  for (int kc = 0; kc < 3; ++kc) {
    const int kb = kc * 32, ka = kb + quad * 8;
    const short8 Ah = *(const short8*)((ka < SA) ? XAh + (m0 + nn) * SA + ka : ZS);
    const short8 Al = *(const short8*)((ka < SA) ? XAl + (m0 + nn) * SA + ka : ZS);
    #pragma unroll
    for (int ct = 0; ct < 4; ++ct) {
      const unsigned short* pb = g_Wb + W1BH + (ct * 16 + nn) * 96 + ka;
      const short8 Bh = *(const short8*)pb;
      const short8 Bl = *(const short8*)(pb + (W1BL - W1BH));
      C[ct] = MFMA_BF16(Ah, Bh, C[ct], 0, 0, 0);
      C[ct] = MFMA_BF16(Al, Bh, C[ct], 0, 0, 0);
      C[ct] = MFMA_BF16(Ah, Bl, C[ct], 0, 0, 0);
    }
  }
  {  // fps layer1 (fp32, R9 scheme)
    const int o = tq >> 1, kh = tq & 1;
    float a2 = 0.f;
    if (kh == 0) {
      for (int k = 0; k < 34; ++k) a2 = fmaf(FS[8 + tg * 64 + k], g_W[W1O + k * 64 + o], a2);
    } else {
      for (int k = 34; k < 64; ++k) a2 = fmaf(FS[8 + tg * 64 + k], g_W[W1O + k * 64 + o], a2);
      #pragma unroll
      for (int d = 0; d < 3; ++d) a2 = fmaf(FS[tg * 4 + d], g_W[W1O + (64 + d) * 64 + o], a2);
    }
    a2 += __shfl_xor(a2, 1);
    if (kh == 0) FS[136 + tg * 128 + o] = fmaxf(a2 + g_W[B1O + o], 0.f);  // F1
  }
  #pragma unroll
  for (int ct = 0; ct < 4; ++ct) {
    #pragma unroll
    for (int r = 0; r < 4; ++r) {
      const int row = m0 + quad * 4 + r, col = ct * 16 + nn;
      float v = fmaxf(C[ct][r] + g_W[B1O + col], 0.f);
      unsigned short hu, lu; split2(v, hu, lu);
      XBh[row * SB + col] = hu; XBl[row * SB + col] = lu;
    }
  }
  __syncthreads();

  // ===== Phase 2: h1(XB,K64) @ W2b -> h2(XA cols0..63); fps-L2 =====
  #pragma unroll
  for (int i = 0; i < 4; ++i) C[i] = (f32x4){0.f, 0.f, 0.f, 0.f};
  #pragma unroll
  for (int kc = 0; kc < 2; ++kc) {
    const int ka = kc * 32 + quad * 8;
    const short8 Ah = *(const short8*)(XBh + (m0 + nn) * SB + ka);
    const short8 Al = *(const short8*)(XBl + (m0 + nn) * SB + ka);
    #pragma unroll
    for (int ct = 0; ct < 4; ++ct) {
      const unsigned short* pb = g_Wb + W2BH + (ct * 16 + nn) * 64 + ka;
      const short8 Bh = *(const short8*)pb;
      const short8 Bl = *(const short8*)(pb + (W2BL - W2BH));
      C[ct] = MFMA_BF16(Ah, Bh, C[ct], 0, 0, 0);
      C[ct] = MFMA_BF16(Al, Bh, C[ct], 0, 0, 0);
      C[ct] = MFMA_BF16(Ah, Bl, C[ct], 0, 0, 0);
    }
  }
  {  // fps layer2: F1 -> F2 (over dead fps-feat)
    const int o = tq >> 1, kh = tq & 1;
    float a2 = 0.f;
    for (int k = kh * 32; k < kh * 32 + 32; ++k)
      a2 = fmaf(FS[136 + tg * 128 + k], g_W[W2O + k * 64 + o], a2);
    a2 += __shfl_xor(a2, 1);
    if (kh == 0) FS[8 + tg * 64 + o] = fmaxf(a2 + g_W[B2O + o], 0.f);
  }
  #pragma unroll
  for (int ct = 0; ct < 4; ++ct) {
    #pragma unroll
    for (int r = 0; r < 4; ++r) {
      const int row = m0 + quad * 4 + r, col = ct * 16 + nn;
      float v = fmaxf(C[ct][r] + g_W[B2O + col], 0.f);
      unsigned short hu, lu; split2(v, hu, lu);
      XAh[row * SA + col] = hu; XAl[row * SA + col] = lu;
    }
  }
  __syncthreads();

  // ===== Phase 3: h2(XA,K64) @ W3b[128][64] -> h3(XH cols0..127); fps-L3 =====
  #pragma unroll
  for (int i = 0; i < 8; ++i) C[i] = (f32x4){0.f, 0.f, 0.f, 0.f};
  #pragma unroll
  for (int kc = 0; kc < 2; ++kc) {
    const int ka = kc * 32 + quad * 8;
    const short8 Ah = *(const short8*)(XAh + (m0 + nn) * SA + ka);
    const short8 Al = *(const short8*)(XAl + (m0 + nn) * SA + ka);
    #pragma unroll
    for (int ct = 0; ct < 8; ++ct) {
      const unsigned short* pb = g_Wb + W3BH + (ct * 16 + nn) * 64 + ka;
      const short8 Bh = *(const short8*)pb;
      const short8 Bl = *(const short8*)(pb + (W3BL - W3BH));
      C[ct] = MFMA_BF16(Ah, Bh, C[ct], 0, 0, 0);
      C[ct] = MFMA_BF16(Al, Bh, C[ct], 0, 0, 0);
      C[ct] = MFMA_BF16(Ah, Bl, C[ct], 0, 0, 0);
    }
  }
  {  // fps layer3: F2 -> F3 (over dead F1)
    const int o = tq;
    float a2 = 0.f;
    for (int k = 0; k < 64; ++k)
      a2 = fmaf(FS[8 + tg * 64 + k], g_W[W3O + k * 128 + o], a2);
    FS[136 + tg * 128 + o] = fmaxf(a2 + g_W[B3O + o], 0.f);
  }
  #pragma unroll
  for (int ct = 0; ct < 8; ++ct) {
    #pragma unroll
    for (int r = 0; r < 4; ++r) {
      const int row = m0 + quad * 4 + r, col = ct * 16 + nn;
      float v = fmaxf(C[ct][r] + g_W[B3O + col], 0.f);
      unsigned short hu, lu; split2(v, hu, lu);
      XHh[row * SHX + col] = hu; XHl[row * SHX + col] = lu;
    }
  }
  __syncthreads();

  // ===== fps ebias: EB = [F3|new_xyz] . A (fp32), overwrites F3 =====
  {
    const int o = tq;
    const float* ap = g_W + AO + (o >> 6) * 8448 + (o & 63);
    float a2 = 0.f;
    for (int k = 0; k < 128; ++k) a2 = fmaf(FS[136 + tg * 128 + k], ap[k * 64], a2);
    #pragma unroll
    for (int d = 0; d < 3; ++d) a2 = fmaf(FS[tg * 4 + d], ap[(128 + d) * 64], a2);
    __syncthreads();
    FS[136 + tg * 128 + o] = a2;   // EB
    __syncthreads();
  }

  // ===== Phase 5: [h3|rxyz](XH,K160) @ Ab[128][160] -> scores; quarters+softmax =====
  #pragma unroll
  for (int i = 0; i < 8; ++i) C[i] = (f32x4){0.f, 0.f, 0.f, 0.f};
  #pragma unroll
  for (int kc = 0; kc < 5; ++kc) {
    const int kb = kc * 32, ka = kb + quad * 8;
    const short8 Ah = *(const short8*)((ka < SHX) ? XHh + (m0 + nn) * SHX + ka : ZS);
    const short8 Al = *(const short8*)((ka < SHX) ? XHl + (m0 + nn) * SHX + ka : ZS);
    #pragma unroll
    for (int ct = 0; ct < 8; ++ct) {
      const unsigned short* pb = g_Wb + ABH + (ct * 16 + nn) * 160 + ka;
      const short8 Bh = *(const short8*)pb;
      const short8 Bl = *(const short8*)(pb + (ABL - ABH));
      C[ct] = MFMA_BF16(Ah, Bh, C[ct], 0, 0, 0);
      C[ct] = MFMA_BF16(Al, Bh, C[ct], 0, 0, 0);
      C[ct] = MFMA_BF16(Ah, Bl, C[ct], 0, 0, 0);
    }
  }
  const int wg = m0 >> 5;   // wave's group
  #pragma unroll
  for (int q = 0; q < 4; ++q) {
    #pragma unroll
    for (int cti = 0; cti < 2; ++cti) {
      const int ct = 2 * q + cti;
      #pragma unroll
      for (int r = 0; r < 4; ++r) {
        const int row = m0 + quad * 4 + r, col = ct * 16 + nn;
        float e = FS[136 + wg * 128 + col] - C[ct][r];
        e = (e > 0.f) ? e : ALPHAn * e;
        EQ[row * 33 + (col - q * 32)] = e;
      }
    }
    __syncthreads();
    if (t < 64) {
      const int sg = t >> 5, c = q * 32 + (t & 31);
      const float* ec = EQ + (sg * 32) * 33 + (t & 31);
      float mx = -3.4e38f;
      #pragma unroll 4
      for (int si = 0; si < 32; ++si) mx = fmaxf(mx, ec[si * 33]);
      float den = 0.f, pool = 0.f;
      #pragma unroll 4
      for (int si = 0; si < 32; ++si) {
        const float w = __expf(ec[si * 33] - mx);
        den += w;
        const int rr = sg * 32 + si;
        const float h3 = bf2f(XHh[rr * SHX + c]) + bf2f(XHl[rr * SHX + c]);
        pool = fmaf(w, h3, pool);
      }
      const int gg2 = blockIdx.x * 2 + sg;
      out[Bn * 3 * Pn + (((gg2 >> 10) * 128) + c) * Pn + (gg2 & 1023)] = pool / den;
    }
    __syncthreads();
  }
}

extern "C" void kernel_launch(void* const* d_in, const int* in_sizes, int n_in,
                              void* d_out, int out_size, void* d_ws, size_t ws_size,
                              hipStream_t stream) {
  const float* xyz       = (const float*)d_in[0];
  const float* points    = (const float*)d_in[1];
  const int*   fps_idx   = (const int*)d_in[2];
  const int*   group_idx = (const int*)d_in[3];

  const int prep_n = WSF + NPAIR;
  prep_kernel<<<(prep_n + 255) / 256, 256, 0, stream>>>(
      (const float*)d_in[4],  (const float*)d_in[5],
      (const float*)d_in[6],  (const float*)d_in[7],
      (const float*)d_in[8],  (const float*)d_in[9],
      (const float*)d_in[10], (const float*)d_in[11],
      (const float*)d_in[12], (const float*)d_in[13],
      (const float*)d_in[14], (const float*)d_in[15],
      (const float*)d_in[16], (const float*)d_in[17],
      (const float*)d_in[18], (const float*)d_in[19],
      (const float*)d_in[20], (const float*)d_in[21],
      (const float*)d_in[22]);

  fused_kernel<<<Bn * Pn / 2, 256, 0, stream>>>(xyz, points, fps_idx, group_idx,
                                                (float*)d_out);
}

// Round 11
// 828.099 us; speedup vs baseline: 1.0338x; 1.0338x over previous
//
#include <hip/hip_runtime.h>
#include <hip/hip_bf16.h>

#define Bn 16
#define Nn 4096
#define Pn 1024
#define Sn 32
#define Cn 64
#define EPSn 1e-5f
#define ALPHAn 0.2f

// ---- fp32 weight table (fps scalar path) ----
#define W1O 0       // [68][64] k-order [feat64|xyz3|pad]
#define W2O 4352    // [64][64]
#define W3O 8448    // [64][128]
#define AO  16640   // two col-halves [132][64]; k-order [h3|xyz|pad]
#define B1O 33536
#define B2O 33600
#define B3O 33664
#define WSF 33792
__device__ __align__(16) float g_W[WSF];

// ---- split-bf16 weights [N][Kpad], h and l planes (u16 units) ----
#define W1BH 0
#define W1BL 6144
#define W2BH 12288
#define W2BL 16384
#define W3BH 20480
#define W3BL 28672
#define ABH  36864
#define ABL  57344
#define WBU  77824
#define NPAIR 38912
__device__ __align__(16) unsigned short g_Wb[WBU];

typedef __attribute__((ext_vector_type(8))) short short8;
typedef __attribute__((ext_vector_type(4))) float f32x4;

__device__ __forceinline__ void split2(float v, unsigned short& hu, unsigned short& lu) {
  __hip_bfloat16 h = __float2bfloat16(v);
  float hv = __bfloat162float(h);
  __hip_bfloat16 l = __float2bfloat16(v - hv);
  hu = *(unsigned short*)&h;
  lu = *(unsigned short*)&l;
}
__device__ __forceinline__ unsigned short bfh(float v) {
  __hip_bfloat16 h = __float2bfloat16(v);
  return *(unsigned short*)&h;
}
__device__ __forceinline__ float bf2f(unsigned short u) {
  __hip_bfloat16 h = *(__hip_bfloat16*)&u;
  return __bfloat162float(h);
}

__global__ void prep_kernel(
    const float* __restrict__ w1, const float* __restrict__ b1,
    const float* __restrict__ g1, const float* __restrict__ bt1,
    const float* __restrict__ m1, const float* __restrict__ v1,
    const float* __restrict__ w2, const float* __restrict__ b2,
    const float* __restrict__ g2, const float* __restrict__ bt2,
    const float* __restrict__ m2, const float* __restrict__ v2,
    const float* __restrict__ w3, const float* __restrict__ b3,
    const float* __restrict__ g3, const float* __restrict__ bt3,
    const float* __restrict__ m3, const float* __restrict__ v3,
    const float* __restrict__ a)
{
  const int idx = blockIdx.x * blockDim.x + threadIdx.x;
  if (idx < WSF) {
    float val;
    if (idx < W2O) {
      const int k = idx >> 6, o = idx & 63;
      const float sc = g1[o] * rsqrtf(v1[o] + EPSn);
      val = (k < 64) ? w1[o * 67 + 3 + k] * sc
          : (k < 67) ? w1[o * 67 + (k - 64)] * sc : 0.f;
    } else if (idx < W3O) {
      const int r = idx - W2O, k = r >> 6, o = r & 63;
      val = w2[o * 64 + k] * (g2[o] * rsqrtf(v2[o] + EPSn));
    } else if (idx < AO) {
      const int r = idx - W3O, k = r >> 7, o = r & 127;
      val = w3[o * 64 + k] * (g3[o] * rsqrtf(v3[o] + EPSn));
    } else if (idx < B1O) {
      int r = idx - AO;
      const int half = r / 8448; r -= half * 8448;
      const int k = r >> 6, o = half * 64 + (r & 63);
      val = (k < 128) ? a[(3 + k) * 128 + o]
          : (k < 131) ? a[(k - 128) * 128 + o] : 0.f;
    } else if (idx < B2O) {
      const int o = idx - B1O;
      val = (b1[o] - m1[o]) * (g1[o] * rsqrtf(v1[o] + EPSn)) + bt1[o];
    } else if (idx < B3O) {
      const int o = idx - B2O;
      val = (b2[o] - m2[o]) * (g2[o] * rsqrtf(v2[o] + EPSn)) + bt2[o];
    } else {
      const int o = idx - B3O;
      val = (b3[o] - m3[o]) * (g3[o] * rsqrtf(v3[o] + EPSn)) + bt3[o];
    }
    g_W[idx] = val;
  } else if (idx < WSF + NPAIR) {
    const int i = idx - WSF;
    float w; int ho, lo;
    if (i < 6144) {                       // W1b [64][96]
      const int n = i / 96, k = i % 96;
      const float s = g1[n] * rsqrtf(v1[n] + EPSn);
      w = (k < 64) ? w1[n * 67 + 3 + k] * s
        : (k < 67) ? w1[n * 67 + (k - 64)] * s : 0.f;
      ho = W1BH + i; lo = W1BL + i;
    } else if (i < 10240) {               // W2b [64][64]
      const int r = i - 6144, n = r >> 6, k = r & 63;
      w = w2[n * 64 + k] * (g2[n] * rsqrtf(v2[n] + EPSn));
      ho = W2BH + r; lo = W2BL + r;
    } else if (i < 18432) {               // W3b [128][64]
      const int r = i - 10240, n = r >> 6, k = r & 63;
      w = w3[n * 64 + k] * (g3[n] * rsqrtf(v3[n] + EPSn));
      ho = W3BH + r; lo = W3BL + r;
    } else {                              // Ab [128][160]
      const int r = i - 18432, n = r / 160, k = r % 160;
      w = (k < 128) ? a[(3 + k) * 128 + n]
        : (k < 131) ? a[(k - 128) * 128 + n] : 0.f;
      ho = ABH + r; lo = ABL + r;
    }
    unsigned short hu, lu; split2(w, hu, lu);
    g_Wb[ho] = hu; g_Wb[lo] = lu;
  }
}

// ---- LDS (bytes), 1 group/block: 40864 B -> 4 blocks/CU, 16 waves/CU ----
// XAh u16[32][80]: input bf16 [feat64|rxyz3|zeros]; h2 reuses cols 0..63.
// XBh u16[32][64]: h1.   XHh u16[32][144]: [h3(128)|rxyz3|zeros].
// EQ  f32[32][129]: scores (stride 129: conflict-free columns).
// FS  f32[196]: newxyz[0..3], FA[4..67] (fpsfeat->F2), FB[68..195] (F1->F3->EB).
#define OXAH 0
#define OXBH 10240
#define OXHH 14336
#define OEQ  23552
#define OFS  40064
#define OZST 40848
#define LDSB 40864

#define MFMA_BF16 __builtin_amdgcn_mfma_f32_16x16x32_bf16

__global__ __launch_bounds__(256, 4) void fused_kernel(
    const float* __restrict__ xyz, const float* __restrict__ points,
    const int* __restrict__ fps_idx, const int* __restrict__ group_idx,
    float* __restrict__ out)
{
  __shared__ __align__(16) unsigned char LB[LDSB];
  unsigned short* XAh = (unsigned short*)(LB + OXAH);
  unsigned short* XBh = (unsigned short*)(LB + OXBH);
  unsigned short* XHh = (unsigned short*)(LB + OXHH);
  float*          EQ  = (float*)(LB + OEQ);
  float*          FS  = (float*)(LB + OFS);
  unsigned short* ZS  = (unsigned short*)(LB + OZST);

  const int t = threadIdx.x, lane = t & 63, wave = t >> 6;
  const int quad = lane >> 4, nn = lane & 15;
  const int mt = wave >> 1, ch = wave & 1;   // wave = row-tile x col-half
  const int m0 = mt * 16;
  const int g = blockIdx.x;
  const int b = g >> 10, p = g & 1023;

  // ---- S0: zero stub; fps point; new_xyz; out0 ----
  if (t < 4) ((float*)ZS)[t] = 0.f;
  {
    const int fi = fps_idx[g];
    if (t < 64) {
      FS[4 + t] = points[b * Cn * Nn + t * Nn + fi];
    } else if (t < 67) {
      const int d = t - 64;
      const float v = xyz[b * 3 * Nn + d * Nn + fi];
      FS[d] = v;
      out[(b * 3 + d) * Pn + p] = v;
    }
  }
  __syncthreads();

  // ---- S1: gather -> XAh bf16; rxyz -> XAh[64..66], XHh[128..130]; zero pads ----
  {
    const int s0 = t >> 3, cg = t & 7;
    const int gi = group_idx[g * Sn + s0];
    const float* prow = points + b * Cn * Nn + gi;
    const int c0 = cg * 8;
    #pragma unroll
    for (int k = 0; k < 8; ++k)
      XAh[s0 * 80 + c0 + k] = bfh(prow[(c0 + k) * Nn]);
    if (cg == 0) {
      #pragma unroll
      for (int d = 0; d < 3; ++d) {
        const float r = xyz[b * 3 * Nn + d * Nn + gi] - FS[d];
        const unsigned short hu = bfh(r);
        XAh[s0 * 80 + 64 + d] = hu;
        XHh[s0 * 144 + 128 + d] = hu;
      }
    } else if (cg == 1) {
      #pragma unroll
      for (int j = 0; j < 13; ++j) XAh[s0 * 80 + 67 + j] = 0;
    } else if (cg == 2) {
      #pragma unroll
      for (int j = 0; j < 13; ++j) XHh[s0 * 144 + 131 + j] = 0;
    }
  }
  __syncthreads();

  f32x4 C[4];

  // ===== Phase 1: X(K96) @ W1b -> h1(XBh); fps-L1 =====
  C[0] = (f32x4){0.f,0.f,0.f,0.f}; C[1] = (f32x4){0.f,0.f,0.f,0.f};
  #pragma unroll
  for (int kc = 0; kc < 3; ++kc) {
    const int ka = kc * 32 + quad * 8;
    const short8 Ah = *(const short8*)((ka < 80) ? XAh + (m0 + nn) * 80 + ka : ZS);
    #pragma unroll
    for (int c = 0; c < 2; ++c) {
      const unsigned short* pb = g_Wb + W1BH + (ch * 32 + c * 16 + nn) * 96 + ka;
      const short8 Bh = *(const short8*)pb;
      const short8 Bl = *(const short8*)(pb + (W1BL - W1BH));
      C[c] = MFMA_BF16(Ah, Bh, C[c], 0, 0, 0);
      C[c] = MFMA_BF16(Ah, Bl, C[c], 0, 0, 0);
    }
  }
  {  // fps layer1 (fp32; duplicated across thread-halves, same-value writes)
    const int o = (t & 127) >> 1, kh = t & 1;
    float a2 = 0.f;
    if (kh == 0) {
      #pragma unroll 2
      for (int k = 0; k < 34; ++k) a2 = fmaf(FS[4 + k], g_W[W1O + k * 64 + o], a2);
    } else {
      #pragma unroll 2
      for (int k = 34; k < 64; ++k) a2 = fmaf(FS[4 + k], g_W[W1O + k * 64 + o], a2);
      #pragma unroll
      for (int d = 0; d < 3; ++d) a2 = fmaf(FS[d], g_W[W1O + (64 + d) * 64 + o], a2);
    }
    a2 += __shfl_xor(a2, 1);
    if (kh == 0) FS[68 + o] = fmaxf(a2 + g_W[B1O + o], 0.f);  // F1
  }
  #pragma unroll
  for (int c = 0; c < 2; ++c) {
    const int col = ch * 32 + c * 16 + nn;
    #pragma unroll
    for (int r = 0; r < 4; ++r) {
      const int row = m0 + quad * 4 + r;
      XBh[row * 64 + col] = bfh(fmaxf(C[c][r] + g_W[B1O + col], 0.f));
    }
  }
  __syncthreads();

  // ===== Phase 2: h1(K64) @ W2b -> h2(XAh cols0..63); fps-L2 =====
  C[0] = (f32x4){0.f,0.f,0.f,0.f}; C[1] = (f32x4){0.f,0.f,0.f,0.f};
  #pragma unroll
  for (int kc = 0; kc < 2; ++kc) {
    const int ka = kc * 32 + quad * 8;
    const short8 Ah = *(const short8*)(XBh + (m0 + nn) * 64 + ka);
    #pragma unroll
    for (int c = 0; c < 2; ++c) {
      const unsigned short* pb = g_Wb + W2BH + (ch * 32 + c * 16 + nn) * 64 + ka;
      const short8 Bh = *(const short8*)pb;
      const short8 Bl = *(const short8*)(pb + (W2BL - W2BH));
      C[c] = MFMA_BF16(Ah, Bh, C[c], 0, 0, 0);
      C[c] = MFMA_BF16(Ah, Bl, C[c], 0, 0, 0);
    }
  }
  {  // fps layer2: F1 -> F2 (over dead fps-feat)
    const int o = (t & 127) >> 1, kh = t & 1;
    float a2 = 0.f;
    #pragma unroll 2
    for (int k = kh * 32; k < kh * 32 + 32; ++k)
      a2 = fmaf(FS[68 + k], g_W[W2O + k * 64 + o], a2);
    a2 += __shfl_xor(a2, 1);
    if (kh == 0) FS[4 + o] = fmaxf(a2 + g_W[B2O + o], 0.f);
  }
  #pragma unroll
  for (int c = 0; c < 2; ++c) {
    const int col = ch * 32 + c * 16 + nn;
    #pragma unroll
    for (int r = 0; r < 4; ++r) {
      const int row = m0 + quad * 4 + r;
      XAh[row * 80 + col] = bfh(fmaxf(C[c][r] + g_W[B2O + col], 0.f));
    }
  }
  __syncthreads();

  // ===== Phase 3: h2(K64) @ W3b -> h3(XHh cols0..127); fps-L3 =====
  #pragma unroll
  for (int i = 0; i < 4; ++i) C[i] = (f32x4){0.f,0.f,0.f,0.f};
  #pragma unroll
  for (int kc = 0; kc < 2; ++kc) {
    const int ka = kc * 32 + quad * 8;
    const short8 Ah = *(const short8*)(XAh + (m0 + nn) * 80 + ka);
    #pragma unroll
    for (int c = 0; c < 4; ++c) {
      const unsigned short* pb = g_Wb + W3BH + (ch * 64 + c * 16 + nn) * 64 + ka;
      const short8 Bh = *(const short8*)pb;
      const short8 Bl = *(const short8*)(pb + (W3BL - W3BH));
      C[c] = MFMA_BF16(Ah, Bh, C[c], 0, 0, 0);
      C[c] = MFMA_BF16(Ah, Bl, C[c], 0, 0, 0);
    }
  }
  {  // fps layer3: F2 -> F3 (FB, over dead F1)
    const int o = t & 127;
    float a2 = 0.f;
    #pragma unroll 4
    for (int k = 0; k < 64; ++k)
      a2 = fmaf(FS[4 + k], g_W[W3O + k * 128 + o], a2);
    FS[68 + o] = fmaxf(a2 + g_W[B3O + o], 0.f);
  }
  #pragma unroll
  for (int c = 0; c < 4; ++c) {
    const int col = ch * 64 + c * 16 + nn;
    #pragma unroll
    for (int r = 0; r < 4; ++r) {
      const int row = m0 + quad * 4 + r;
      XHh[row * 144 + col] = bfh(fmaxf(C[c][r] + g_W[B3O + col], 0.f));
    }
  }
  __syncthreads();

  // ===== ebias: EB = [F3|new_xyz] . A (fp32); overwrites F3 =====
  {
    const int o = t & 127;
    const float* ap = g_W + AO + (o >> 6) * 8448 + (o & 63);
    float a2 = 0.f;
    #pragma unroll 4
    for (int k = 0; k < 128; ++k) a2 = fmaf(FS[68 + k], ap[k * 64], a2);
    #pragma unroll
    for (int d = 0; d < 3; ++d) a2 = fmaf(FS[d], ap[(128 + d) * 64], a2);
    __syncthreads();
    FS[68 + o] = a2;   // EB
    __syncthreads();
  }

  // ===== Phase 5: [h3|rxyz](K160) @ Ab -> scores -> EQ =====
  #pragma unroll
  for (int i = 0; i < 4; ++i) C[i] = (f32x4){0.f,0.f,0.f,0.f};
  #pragma unroll
  for (int kc = 0; kc < 5; ++kc) {
    const int ka = kc * 32 + quad * 8;
    const short8 Ah = *(const short8*)((ka < 144) ? XHh + (m0 + nn) * 144 + ka : ZS);
    #pragma unroll
    for (int c = 0; c < 4; ++c) {
      const unsigned short* pb = g_Wb + ABH + (ch * 64 + c * 16 + nn) * 160 + ka;
      const short8 Bh = *(const short8*)pb;
      const short8 Bl = *(const short8*)(pb + (ABL - ABH));
      C[c] = MFMA_BF16(Ah, Bh, C[c], 0, 0, 0);
      C[c] = MFMA_BF16(Ah, Bl, C[c], 0, 0, 0);
    }
  }
  #pragma unroll
  for (int c = 0; c < 4; ++c) {
    const int col = ch * 64 + c * 16 + nn;
    #pragma unroll
    for (int r = 0; r < 4; ++r) {
      const int row = m0 + quad * 4 + r;
      float e = FS[68 + col] - C[c][r];
      EQ[row * 129 + col] = (e > 0.f) ? e : ALPHAn * e;
    }
  }
  __syncthreads();

  // ===== softmax over s + pooled sum; out1 =====
  if (t < 128) {
    const int c = t;
    const float* ec = EQ + c;
    float mx = -3.4e38f;
    #pragma unroll 4
    for (int si = 0; si < 32; ++si) mx = fmaxf(mx, ec[si * 129]);
    float den = 0.f, pool = 0.f;
    #pragma unroll 4
    for (int si = 0; si < 32; ++si) {
      const float w = __expf(ec[si * 129] - mx);
      den += w;
      pool = fmaf(w, bf2f(XHh[si * 144 + c]), pool);
    }
    out[Bn * 3 * Pn + (b * 128 + c) * Pn + p] = pool / den;
  }
}

extern "C" void kernel_launch(void* const* d_in, const int* in_sizes, int n_in,
                              void* d_out, int out_size, void* d_ws, size_t ws_size,
                              hipStream_t stream) {
  const float* xyz       = (const float*)d_in[0];
  const float* points    = (const float*)d_in[1];
  const int*   fps_idx   = (const int*)d_in[2];
  const int*   group_idx = (const int*)d_in[3];

  const int prep_n = WSF + NPAIR;
  prep_kernel<<<(prep_n + 255) / 256, 256, 0, stream>>>(
      (const float*)d_in[4],  (const float*)d_in[5],
      (const float*)d_in[6],  (const float*)d_in[7],
      (const float*)d_in[8],  (const float*)d_in[9],
      (const float*)d_in[10], (const float*)d_in[11],
      (const float*)d_in[12], (const float*)d_in[13],
      (const float*)d_in[14], (const float*)d_in[15],
      (const float*)d_in[16], (const float*)d_in[17],
      (const float*)d_in[18], (const float*)d_in[19],
      (const float*)d_in[20], (const float*)d_in[21],
      (const float*)d_in[22]);

  fused_kernel<<<Bn * Pn, 256, 0, stream>>>(xyz, points, fps_idx, group_idx,
                                            (float*)d_out);
}

// Round 12
// 774.544 us; speedup vs baseline: 1.1053x; 1.0691x over previous
//
#include <hip/hip_runtime.h>
#include <hip/hip_bf16.h>

#define Bn 16
#define Nn 4096
#define Pn 1024
#define Sn 32
#define Cn 64
#define EPSn 1e-5f
#define ALPHAn 0.2f

// ---- fp32 weight table (fps scalar path) ----
#define W1O 0       // [68][64] k-order [feat64|xyz3|pad]
#define W2O 4352    // [64][64]
#define W3O 8448    // [64][128]
#define AO  16640   // two col-halves [132][64]; k-order [h3|xyz|pad]
#define B1O 33536
#define B2O 33600
#define B3O 33664
#define WSF 33792
__device__ __align__(16) float g_W[WSF];

// ---- split-bf16 weights [N][Kpad], h and l planes ----
#define W1BH 0
#define W1BL 6144
#define W2BH 12288
#define W2BL 16384
#define W3BH 20480
#define W3BL 28672
#define ABH  36864
#define ABL  57344
#define WBU  77824
#define NPAIR 38912
__device__ __align__(16) unsigned short g_Wb[WBU];

// ---- row-major point store [b][n][68] = [feat64|xyz3|pad0] (R12: kills the
// 67-lines-per-neighbor gather; one neighbor = one 272B row) ----
__device__ __align__(16) float g_pts[Bn * Nn * 68];
// ---- dense out1 staging [b][p][128]; epilogue transposes to [b][128][p] ----
__device__ __align__(16) float g_tmp[Bn * Pn * 128];

typedef __attribute__((ext_vector_type(8))) short short8;
typedef __attribute__((ext_vector_type(4))) float f32x4;

__device__ __forceinline__ void split2(float v, unsigned short& hu, unsigned short& lu) {
  __hip_bfloat16 h = __float2bfloat16(v);
  float hv = __bfloat162float(h);
  __hip_bfloat16 l = __float2bfloat16(v - hv);
  hu = *(unsigned short*)&h;
  lu = *(unsigned short*)&l;
}
__device__ __forceinline__ unsigned short bfh(float v) {
  __hip_bfloat16 h = __float2bfloat16(v);
  return *(unsigned short*)&h;
}
__device__ __forceinline__ float bf2f(unsigned short u) {
  __hip_bfloat16 h = *(__hip_bfloat16*)&u;
  return __bfloat162float(h);
}

__global__ void prep_kernel(
    const float* __restrict__ w1, const float* __restrict__ b1,
    const float* __restrict__ g1, const float* __restrict__ bt1,
    const float* __restrict__ m1, const float* __restrict__ v1,
    const float* __restrict__ w2, const float* __restrict__ b2,
    const float* __restrict__ g2, const float* __restrict__ bt2,
    const float* __restrict__ m2, const float* __restrict__ v2,
    const float* __restrict__ w3, const float* __restrict__ b3,
    const float* __restrict__ g3, const float* __restrict__ bt3,
    const float* __restrict__ m3, const float* __restrict__ v3,
    const float* __restrict__ a)
{
  const int idx = blockIdx.x * blockDim.x + threadIdx.x;
  if (idx < WSF) {
    float val;
    if (idx < W2O) {
      const int k = idx >> 6, o = idx & 63;
      const float sc = g1[o] * rsqrtf(v1[o] + EPSn);
      val = (k < 64) ? w1[o * 67 + 3 + k] * sc
          : (k < 67) ? w1[o * 67 + (k - 64)] * sc : 0.f;
    } else if (idx < W3O) {
      const int r = idx - W2O, k = r >> 6, o = r & 63;
      val = w2[o * 64 + k] * (g2[o] * rsqrtf(v2[o] + EPSn));
    } else if (idx < AO) {
      const int r = idx - W3O, k = r >> 7, o = r & 127;
      val = w3[o * 64 + k] * (g3[o] * rsqrtf(v3[o] + EPSn));
    } else if (idx < B1O) {
      int r = idx - AO;
      const int half = r / 8448; r -= half * 8448;
      const int k = r >> 6, o = half * 64 + (r & 63);
      val = (k < 128) ? a[(3 + k) * 128 + o]
          : (k < 131) ? a[(k - 128) * 128 + o] : 0.f;
    } else if (idx < B2O) {
      const int o = idx - B1O;
      val = (b1[o] - m1[o]) * (g1[o] * rsqrtf(v1[o] + EPSn)) + bt1[o];
    } else if (idx < B3O) {
      const int o = idx - B2O;
      val = (b2[o] - m2[o]) * (g2[o] * rsqrtf(v2[o] + EPSn)) + bt2[o];
    } else {
      const int o = idx - B3O;
      val = (b3[o] - m3[o]) * (g3[o] * rsqrtf(v3[o] + EPSn)) + bt3[o];
    }
    g_W[idx] = val;
  } else if (idx < WSF + NPAIR) {
    const int i = idx - WSF;
    float w; int ho, lo;
    if (i < 6144) {
      const int n = i / 96, k = i % 96;
      const float s = g1[n] * rsqrtf(v1[n] + EPSn);
      w = (k < 64) ? w1[n * 67 + 3 + k] * s
        : (k < 67) ? w1[n * 67 + (k - 64)] * s : 0.f;
      ho = W1BH + i; lo = W1BL + i;
    } else if (i < 10240) {
      const int r = i - 6144, n = r >> 6, k = r & 63;
      w = w2[n * 64 + k] * (g2[n] * rsqrtf(v2[n] + EPSn));
      ho = W2BH + r; lo = W2BL + r;
    } else if (i < 18432) {
      const int r = i - 10240, n = r >> 6, k = r & 63;
      w = w3[n * 64 + k] * (g3[n] * rsqrtf(v3[n] + EPSn));
      ho = W3BH + r; lo = W3BL + r;
    } else {
      const int r = i - 18432, n = r / 160, k = r % 160;
      w = (k < 128) ? a[(3 + k) * 128 + n]
        : (k < 131) ? a[(k - 128) * 128 + n] : 0.f;
      ho = ABH + r; lo = ABL + r;
    }
    unsigned short hu, lu; split2(w, hu, lu);
    g_Wb[ho] = hu; g_Wb[lo] = lu;
  }
}

// Tiled transpose: points[b][c][n] + xyz[b][d][n] -> g_pts[b][n][68]
__global__ __launch_bounds__(256) void transpose_pts(
    const float* __restrict__ xyz, const float* __restrict__ points)
{
  __shared__ float T[68 * 65];
  const int t = threadIdx.x;
  const int b = blockIdx.x >> 6, n0 = (blockIdx.x & 63) << 6;
  const int nn = t & 63, cgrp = t >> 6;
  #pragma unroll
  for (int k = 0; k < 16; ++k) {
    const int c = cgrp * 16 + k;
    T[c * 65 + nn] = points[(b * Cn + c) * Nn + n0 + nn];
  }
  if (cgrp == 0) {
    #pragma unroll
    for (int d = 0; d < 3; ++d)
      T[(64 + d) * 65 + nn] = xyz[(b * 3 + d) * Nn + n0 + nn];
    T[67 * 65 + nn] = 0.f;
  }
  __syncthreads();
  const int row = t >> 2, j0 = (t & 3) * 17;
  float* dst = g_pts + (((long)b << 12) + n0 + row) * 68 + j0;
  #pragma unroll
  for (int j = 0; j < 17; ++j) dst[j] = T[(j0 + j) * 65 + row];
}

// Epilogue: g_tmp[b][p][128] -> out1[b][c][p]
__global__ __launch_bounds__(256) void transpose_out(float* __restrict__ out)
{
  __shared__ float T[64 * 129];
  const int t = threadIdx.x;
  const int b = blockIdx.x >> 4, p0 = (blockIdx.x & 15) << 6;
  const int c = t & 127, ph = t >> 7;
  #pragma unroll
  for (int pp = 0; pp < 32; ++pp) {
    const int pi = ph * 32 + pp;
    T[pi * 129 + c] = g_tmp[(((long)b << 10) + p0 + pi) * 128 + c];
  }
  __syncthreads();
  const int pn = t & 63, cg = t >> 6;
  #pragma unroll
  for (int k = 0; k < 32; ++k) {
    const int cc = cg * 32 + k;
    out[Bn * 3 * Pn + ((b << 7) + cc) * Pn + p0 + pn] = T[pn * 129 + cc];
  }
}

// ---- LDS (bytes), 1 group/block: 40864 B -> 4 blocks/CU ----
#define OXAH 0
#define OXBH 10240
#define OXHH 14336
#define OEQ  23552
#define OFS  40064
#define OZST 40848
#define LDSB 40864

#define MFMA_BF16 __builtin_amdgcn_mfma_f32_16x16x32_bf16

__global__ __launch_bounds__(256, 4) void fused_kernel(
    const int* __restrict__ fps_idx, const int* __restrict__ group_idx,
    float* __restrict__ out)
{
  __shared__ __align__(16) unsigned char LB[LDSB];
  unsigned short* XAh = (unsigned short*)(LB + OXAH);
  unsigned short* XBh = (unsigned short*)(LB + OXBH);
  unsigned short* XHh = (unsigned short*)(LB + OXHH);
  float*          EQ  = (float*)(LB + OEQ);
  float*          FS  = (float*)(LB + OFS);
  unsigned short* ZS  = (unsigned short*)(LB + OZST);

  const int t = threadIdx.x, lane = t & 63, wave = t >> 6;
  const int quad = lane >> 4, nn = lane & 15;
  const int mt = wave >> 1, ch = wave & 1;
  const int m0 = mt * 16;
  const int g = blockIdx.x;
  const int b = g >> 10, p = g & 1023;

  // ---- S0: zero stub; fps row (one 272B read); out0 ----
  if (t < 4) ((float*)ZS)[t] = 0.f;
  {
    const int fi = fps_idx[g];
    const float* frow = g_pts + (((long)b << 12) + fi) * 68;
    if (t < 64) {
      FS[4 + t] = frow[t];
    } else if (t < 67) {
      const int d = t - 64;
      const float v = frow[t];
      FS[d] = v;
      out[(b * 3 + d) * Pn + p] = v;
    }
  }
  __syncthreads();

  // ---- S1: gather from g_pts rows (float4 pairs); rxyz; zero pads ----
  {
    const int s0 = t >> 3, cg = t & 7;
    const int gi = group_idx[g * Sn + s0];
    const float* prow = g_pts + (((long)b << 12) + gi) * 68;
    const int c0 = cg * 8;
    const float4 va = *(const float4*)(prow + c0);
    const float4 vb = *(const float4*)(prow + c0 + 4);
    XAh[s0 * 80 + c0 + 0] = bfh(va.x); XAh[s0 * 80 + c0 + 1] = bfh(va.y);
    XAh[s0 * 80 + c0 + 2] = bfh(va.z); XAh[s0 * 80 + c0 + 3] = bfh(va.w);
    XAh[s0 * 80 + c0 + 4] = bfh(vb.x); XAh[s0 * 80 + c0 + 5] = bfh(vb.y);
    XAh[s0 * 80 + c0 + 6] = bfh(vb.z); XAh[s0 * 80 + c0 + 7] = bfh(vb.w);
    if (cg == 0) {
      #pragma unroll
      for (int d = 0; d < 3; ++d) {
        const float r = prow[64 + d] - FS[d];
        const unsigned short hu = bfh(r);
        XAh[s0 * 80 + 64 + d] = hu;
        XHh[s0 * 144 + 128 + d] = hu;
      }
    } else if (cg == 1) {
      #pragma unroll
      for (int j = 0; j < 13; ++j) XAh[s0 * 80 + 67 + j] = 0;
    } else if (cg == 2) {
      #pragma unroll
      for (int j = 0; j < 13; ++j) XHh[s0 * 144 + 131 + j] = 0;
    }
  }
  __syncthreads();

  f32x4 C[4];

  // ===== Phase 1: X(K96) @ W1b -> h1(XBh); fps-L1 =====
  C[0] = (f32x4){0.f,0.f,0.f,0.f}; C[1] = (f32x4){0.f,0.f,0.f,0.f};
  #pragma unroll
  for (int kc = 0; kc < 3; ++kc) {
    const int ka = kc * 32 + quad * 8;
    const short8 Ah = *(const short8*)((ka < 80) ? XAh + (m0 + nn) * 80 + ka : ZS);
    #pragma unroll
    for (int c = 0; c < 2; ++c) {
      const unsigned short* pb = g_Wb + W1BH + (ch * 32 + c * 16 + nn) * 96 + ka;
      const short8 Bh = *(const short8*)pb;
      const short8 Bl = *(const short8*)(pb + (W1BL - W1BH));
      C[c] = MFMA_BF16(Ah, Bh, C[c], 0, 0, 0);
      C[c] = MFMA_BF16(Ah, Bl, C[c], 0, 0, 0);
    }
  }
  {
    const int o = (t & 127) >> 1, kh = t & 1;
    float a2 = 0.f;
    if (kh == 0) {
      #pragma unroll 2
      for (int k = 0; k < 34; ++k) a2 = fmaf(FS[4 + k], g_W[W1O + k * 64 + o], a2);
    } else {
      #pragma unroll 2
      for (int k = 34; k < 64; ++k) a2 = fmaf(FS[4 + k], g_W[W1O + k * 64 + o], a2);
      #pragma unroll
      for (int d = 0; d < 3; ++d) a2 = fmaf(FS[d], g_W[W1O + (64 + d) * 64 + o], a2);
    }
    a2 += __shfl_xor(a2, 1);
    if (kh == 0) FS[68 + o] = fmaxf(a2 + g_W[B1O + o], 0.f);
  }
  #pragma unroll
  for (int c = 0; c < 2; ++c) {
    const int col = ch * 32 + c * 16 + nn;
    #pragma unroll
    for (int r = 0; r < 4; ++r) {
      const int row = m0 + quad * 4 + r;
      XBh[row * 64 + col] = bfh(fmaxf(C[c][r] + g_W[B1O + col], 0.f));
    }
  }
  __syncthreads();

  // ===== Phase 2: h1(K64) @ W2b -> h2(XAh cols0..63); fps-L2 =====
  C[0] = (f32x4){0.f,0.f,0.f,0.f}; C[1] = (f32x4){0.f,0.f,0.f,0.f};
  #pragma unroll
  for (int kc = 0; kc < 2; ++kc) {
    const int ka = kc * 32 + quad * 8;
    const short8 Ah = *(const short8*)(XBh + (m0 + nn) * 64 + ka);
    #pragma unroll
    for (int c = 0; c < 2; ++c) {
      const unsigned short* pb = g_Wb + W2BH + (ch * 32 + c * 16 + nn) * 64 + ka;
      const short8 Bh = *(const short8*)pb;
      const short8 Bl = *(const short8*)(pb + (W2BL - W2BH));
      C[c] = MFMA_BF16(Ah, Bh, C[c], 0, 0, 0);
      C[c] = MFMA_BF16(Ah, Bl, C[c], 0, 0, 0);
    }
  }
  {
    const int o = (t & 127) >> 1, kh = t & 1;
    float a2 = 0.f;
    #pragma unroll 2
    for (int k = kh * 32; k < kh * 32 + 32; ++k)
      a2 = fmaf(FS[68 + k], g_W[W2O + k * 64 + o], a2);
    a2 += __shfl_xor(a2, 1);
    if (kh == 0) FS[4 + o] = fmaxf(a2 + g_W[B2O + o], 0.f);
  }
  #pragma unroll
  for (int c = 0; c < 2; ++c) {
    const int col = ch * 32 + c * 16 + nn;
    #pragma unroll
    for (int r = 0; r < 4; ++r) {
      const int row = m0 + quad * 4 + r;
      XAh[row * 80 + col] = bfh(fmaxf(C[c][r] + g_W[B2O + col], 0.f));
    }
  }
  __syncthreads();

  // ===== Phase 3: h2(K64) @ W3b -> h3(XHh cols0..127); fps-L3 =====
  #pragma unroll
  for (int i = 0; i < 4; ++i) C[i] = (f32x4){0.f,0.f,0.f,0.f};
  #pragma unroll
  for (int kc = 0; kc < 2; ++kc) {
    const int ka = kc * 32 + quad * 8;
    const short8 Ah = *(const short8*)(XAh + (m0 + nn) * 80 + ka);
    #pragma unroll
    for (int c = 0; c < 4; ++c) {
      const unsigned short* pb = g_Wb + W3BH + (ch * 64 + c * 16 + nn) * 64 + ka;
      const short8 Bh = *(const short8*)pb;
      const short8 Bl = *(const short8*)(pb + (W3BL - W3BH));
      C[c] = MFMA_BF16(Ah, Bh, C[c], 0, 0, 0);
      C[c] = MFMA_BF16(Ah, Bl, C[c], 0, 0, 0);
    }
  }
  {
    const int o = t & 127;
    float a2 = 0.f;
    #pragma unroll 4
    for (int k = 0; k < 64; ++k)
      a2 = fmaf(FS[4 + k], g_W[W3O + k * 128 + o], a2);
    FS[68 + o] = fmaxf(a2 + g_W[B3O + o], 0.f);
  }
  #pragma unroll
  for (int c = 0; c < 4; ++c) {
    const int col = ch * 64 + c * 16 + nn;
    #pragma unroll
    for (int r = 0; r < 4; ++r) {
      const int row = m0 + quad * 4 + r;
      XHh[row * 144 + col] = bfh(fmaxf(C[c][r] + g_W[B3O + col], 0.f));
    }
  }
  __syncthreads();

  // ===== ebias (fp32); overwrites F3 =====
  {
    const int o = t & 127;
    const float* ap = g_W + AO + (o >> 6) * 8448 + (o & 63);
    float a2 = 0.f;
    #pragma unroll 4
    for (int k = 0; k < 128; ++k) a2 = fmaf(FS[68 + k], ap[k * 64], a2);
    #pragma unroll
    for (int d = 0; d < 3; ++d) a2 = fmaf(FS[d], ap[(128 + d) * 64], a2);
    __syncthreads();
    FS[68 + o] = a2;
    __syncthreads();
  }

  // ===== Phase 5: scores -> EQ =====
  #pragma unroll
  for (int i = 0; i < 4; ++i) C[i] = (f32x4){0.f,0.f,0.f,0.f};
  #pragma unroll
  for (int kc = 0; kc < 5; ++kc) {
    const int ka = kc * 32 + quad * 8;
    const short8 Ah = *(const short8*)((ka < 144) ? XHh + (m0 + nn) * 144 + ka : ZS);
    #pragma unroll
    for (int c = 0; c < 4; ++c) {
      const unsigned short* pb = g_Wb + ABH + (ch * 64 + c * 16 + nn) * 160 + ka;
      const short8 Bh = *(const short8*)pb;
      const short8 Bl = *(const short8*)(pb + (ABL - ABH));
      C[c] = MFMA_BF16(Ah, Bh, C[c], 0, 0, 0);
      C[c] = MFMA_BF16(Ah, Bl, C[c], 0, 0, 0);
    }
  }
  #pragma unroll
  for (int c = 0; c < 4; ++c) {
    const int col = ch * 64 + c * 16 + nn;
    #pragma unroll
    for (int r = 0; r < 4; ++r) {
      const int row = m0 + quad * 4 + r;
      float e = FS[68 + col] - C[c][r];
      EQ[row * 129 + col] = (e > 0.f) ? e : ALPHAn * e;
    }
  }
  __syncthreads();

  // ===== softmax + pooled sum -> g_tmp (dense) =====
  if (t < 128) {
    const int c = t;
    const float* ec = EQ + c;
    float mx = -3.4e38f;
    #pragma unroll 4
    for (int si = 0; si < 32; ++si) mx = fmaxf(mx, ec[si * 129]);
    float den = 0.f, pool = 0.f;
    #pragma unroll 4
    for (int si = 0; si < 32; ++si) {
      const float w = __expf(ec[si * 129] - mx);
      den += w;
      pool = fmaf(w, bf2f(XHh[si * 144 + c]), pool);
    }
    g_tmp[(long)g * 128 + c] = pool / den;
  }
}

extern "C" void kernel_launch(void* const* d_in, const int* in_sizes, int n_in,
                              void* d_out, int out_size, void* d_ws, size_t ws_size,
                              hipStream_t stream) {
  const float* xyz       = (const float*)d_in[0];
  const float* points    = (const float*)d_in[1];
  const int*   fps_idx   = (const int*)d_in[2];
  const int*   group_idx = (const int*)d_in[3];

  const int prep_n = WSF + NPAIR;
  prep_kernel<<<(prep_n + 255) / 256, 256, 0, stream>>>(
      (const float*)d_in[4],  (const float*)d_in[5],
      (const float*)d_in[6],  (const float*)d_in[7],
      (const float*)d_in[8],  (const float*)d_in[9],
      (const float*)d_in[10], (const float*)d_in[11],
      (const float*)d_in[12], (const float*)d_in[13],
      (const float*)d_in[14], (const float*)d_in[15],
      (const float*)d_in[16], (const float*)d_in[17],
      (const float*)d_in[18], (const float*)d_in[19],
      (const float*)d_in[20], (const float*)d_in[21],
      (const float*)d_in[22]);

  transpose_pts<<<Bn * 64, 256, 0, stream>>>(xyz, points);

  fused_kernel<<<Bn * Pn, 256, 0, stream>>>(fps_idx, group_idx, (float*)d_out);

  transpose_out<<<Bn * 16, 256, 0, stream>>>((float*)d_out);
}

// Round 13
// 771.314 us; speedup vs baseline: 1.1099x; 1.0042x over previous
//
#include <hip/hip_runtime.h>
#include <hip/hip_bf16.h>

#define Bn 16
#define Nn 4096
#define Pn 1024
#define Sn 32
#define Cn 64
#define EPSn 1e-5f
#define ALPHAn 0.2f

// ---- fp32 weight table (fps scalar path) ----
#define W1O 0       // [68][64] k-order [feat64|xyz3|pad]
#define W2O 4352    // [64][64]
#define W3O 8448    // [64][128]
#define AO  16640   // two col-halves [132][64]; k-order [h3|xyz|pad]
#define B1O 33536
#define B2O 33600
#define B3O 33664
#define WSF 33792
__device__ __align__(16) float g_W[WSF];

// ---- split-bf16 weights [N][Kpad], h and l planes ----
#define W1BH 0
#define W1BL 6144
#define W2BH 12288
#define W2BL 16384
#define W3BH 20480
#define W3BL 28672
#define ABH  36864
#define ABL  57344
#define WBU  77824
#define NPAIR 38912
__device__ __align__(16) unsigned short g_Wb[WBU];

// ---- row-major point store [b][n][68]; dense out1 staging ----
__device__ __align__(16) float g_pts[Bn * Nn * 68];
__device__ __align__(16) float g_tmp[Bn * Pn * 128];

typedef __attribute__((ext_vector_type(8))) short short8;
typedef __attribute__((ext_vector_type(4))) float f32x4;

__device__ __forceinline__ void split2(float v, unsigned short& hu, unsigned short& lu) {
  __hip_bfloat16 h = __float2bfloat16(v);
  float hv = __bfloat162float(h);
  __hip_bfloat16 l = __float2bfloat16(v - hv);
  hu = *(unsigned short*)&h;
  lu = *(unsigned short*)&l;
}
__device__ __forceinline__ unsigned short bfh(float v) {
  __hip_bfloat16 h = __float2bfloat16(v);
  return *(unsigned short*)&h;
}
__device__ __forceinline__ float bf2f(unsigned short u) {
  __hip_bfloat16 h = *(__hip_bfloat16*)&u;
  return __bfloat162float(h);
}

// Merged prep: blocks [0,1024) transpose points->g_pts; blocks [1024,..) fold weights.
__global__ __launch_bounds__(256) void prep_kernel(
    const float* __restrict__ xyz, const float* __restrict__ points,
    const float* __restrict__ w1, const float* __restrict__ b1,
    const float* __restrict__ g1, const float* __restrict__ bt1,
    const float* __restrict__ m1, const float* __restrict__ v1,
    const float* __restrict__ w2, const float* __restrict__ b2,
    const float* __restrict__ g2, const float* __restrict__ bt2,
    const float* __restrict__ m2, const float* __restrict__ v2,
    const float* __restrict__ w3, const float* __restrict__ b3,
    const float* __restrict__ g3, const float* __restrict__ bt3,
    const float* __restrict__ m3, const float* __restrict__ v3,
    const float* __restrict__ a)
{
  if (blockIdx.x < 1024) {   // transpose tile
    __shared__ float T[68 * 65];
    const int t = threadIdx.x;
    const int b = blockIdx.x >> 6, n0 = (blockIdx.x & 63) << 6;
    const int nn = t & 63, cgrp = t >> 6;
    #pragma unroll
    for (int k = 0; k < 16; ++k) {
      const int c = cgrp * 16 + k;
      T[c * 65 + nn] = points[(b * Cn + c) * Nn + n0 + nn];
    }
    if (cgrp == 0) {
      #pragma unroll
      for (int d = 0; d < 3; ++d)
        T[(64 + d) * 65 + nn] = xyz[(b * 3 + d) * Nn + n0 + nn];
      T[67 * 65 + nn] = 0.f;
    }
    __syncthreads();
    const int row = t >> 2, j0 = (t & 3) * 17;
    float* dst = g_pts + (((long)b << 12) + n0 + row) * 68 + j0;
    #pragma unroll
    for (int j = 0; j < 17; ++j) dst[j] = T[(j0 + j) * 65 + row];
    return;
  }
  const int idx = (blockIdx.x - 1024) * blockDim.x + threadIdx.x;
  if (idx < WSF) {
    float val;
    if (idx < W2O) {
      const int k = idx >> 6, o = idx & 63;
      const float sc = g1[o] * rsqrtf(v1[o] + EPSn);
      val = (k < 64) ? w1[o * 67 + 3 + k] * sc
          : (k < 67) ? w1[o * 67 + (k - 64)] * sc : 0.f;
    } else if (idx < W3O) {
      const int r = idx - W2O, k = r >> 6, o = r & 63;
      val = w2[o * 64 + k] * (g2[o] * rsqrtf(v2[o] + EPSn));
    } else if (idx < AO) {
      const int r = idx - W3O, k = r >> 7, o = r & 127;
      val = w3[o * 64 + k] * (g3[o] * rsqrtf(v3[o] + EPSn));
    } else if (idx < B1O) {
      int r = idx - AO;
      const int half = r / 8448; r -= half * 8448;
      const int k = r >> 6, o = half * 64 + (r & 63);
      val = (k < 128) ? a[(3 + k) * 128 + o]
          : (k < 131) ? a[(k - 128) * 128 + o] : 0.f;
    } else if (idx < B2O) {
      const int o = idx - B1O;
      val = (b1[o] - m1[o]) * (g1[o] * rsqrtf(v1[o] + EPSn)) + bt1[o];
    } else if (idx < B3O) {
      const int o = idx - B2O;
      val = (b2[o] - m2[o]) * (g2[o] * rsqrtf(v2[o] + EPSn)) + bt2[o];
    } else {
      const int o = idx - B3O;
      val = (b3[o] - m3[o]) * (g3[o] * rsqrtf(v3[o] + EPSn)) + bt3[o];
    }
    g_W[idx] = val;
  } else if (idx < WSF + NPAIR) {
    const int i = idx - WSF;
    float w; int ho, lo;
    if (i < 6144) {
      const int n = i / 96, k = i % 96;
      const float s = g1[n] * rsqrtf(v1[n] + EPSn);
      w = (k < 64) ? w1[n * 67 + 3 + k] * s
        : (k < 67) ? w1[n * 67 + (k - 64)] * s : 0.f;
      ho = W1BH + i; lo = W1BL + i;
    } else if (i < 10240) {
      const int r = i - 6144, n = r >> 6, k = r & 63;
      w = w2[n * 64 + k] * (g2[n] * rsqrtf(v2[n] + EPSn));
      ho = W2BH + r; lo = W2BL + r;
    } else if (i < 18432) {
      const int r = i - 10240, n = r >> 6, k = r & 63;
      w = w3[n * 64 + k] * (g3[n] * rsqrtf(v3[n] + EPSn));
      ho = W3BH + r; lo = W3BL + r;
    } else {
      const int r = i - 18432, n = r / 160, k = r % 160;
      w = (k < 128) ? a[(3 + k) * 128 + n]
        : (k < 131) ? a[(k - 128) * 128 + n] : 0.f;
      ho = ABH + r; lo = ABL + r;
    }
    unsigned short hu, lu; split2(w, hu, lu);
    g_Wb[ho] = hu; g_Wb[lo] = lu;
  }
}

// Epilogue: g_tmp[b][p][128] -> out1[b][c][p]
__global__ __launch_bounds__(256) void transpose_out(float* __restrict__ out)
{
  __shared__ float T[64 * 129];
  const int t = threadIdx.x;
  const int b = blockIdx.x >> 4, p0 = (blockIdx.x & 15) << 6;
  const int c = t & 127, ph = t >> 7;
  #pragma unroll
  for (int pp = 0; pp < 32; ++pp) {
    const int pi = ph * 32 + pp;
    T[pi * 129 + c] = g_tmp[(((long)b << 10) + p0 + pi) * 128 + c];
  }
  __syncthreads();
  const int pn = t & 63, cg = t >> 6;
  #pragma unroll
  for (int k = 0; k < 32; ++k) {
    const int cc = cg * 32 + k;
    out[Bn * 3 * Pn + ((b << 7) + cc) * Pn + p0 + pn] = T[pn * 129 + cc];
  }
}

// ---- LDS (bytes), 1 group/block: 40864 B -> 4 blocks/CU ----
#define OXAH 0
#define OXBH 10240
#define OXHH 14336
#define OEQ  23552
#define OFS  40064
#define OZST 40848
#define LDSB 40864

#define MFMA_BF16 __builtin_amdgcn_mfma_f32_16x16x32_bf16

struct B4 { short8 h[4]; short8 l[4]; };

// Double-buffered MFMA phase: buffer for kc is bufs[(P0+kc)&1]; prefetch kc+1
// during kc's MFMAs; at last kc, cross-phase prefetch next phase's kc0 into the
// free buffer (parity (P0+KC)&1) so it is in flight across the barrier.
template<int KC, int C, int P0, bool PF, int NC>
__device__ __forceinline__ void run_phase(
    const unsigned short* __restrict__ Wb, int lo, int kstr, int colb,
    const unsigned short* __restrict__ XA, int ast, int amax,
    const unsigned short* __restrict__ ZS,
    int nn, int quad, int m0,
    const unsigned short* __restrict__ nWb, int nlo, int nkstr, int ncolb,
    B4* bufs, f32x4* Cacc)
{
  #pragma unroll
  for (int kc = 0; kc < KC; ++kc) {
    B4& cur = bufs[(P0 + kc) & 1];
    B4& alt = bufs[(P0 + kc + 1) & 1];
    if (kc + 1 < KC) {
      #pragma unroll
      for (int c = 0; c < C; ++c) {
        const unsigned short* p = Wb + (colb + c * 16 + nn) * kstr + (kc + 1) * 32 + quad * 8;
        alt.h[c] = *(const short8*)p;
        alt.l[c] = *(const short8*)(p + lo);
      }
    } else if (PF) {
      #pragma unroll
      for (int c = 0; c < NC; ++c) {
        const unsigned short* p = nWb + (ncolb + c * 16 + nn) * nkstr + quad * 8;
        alt.h[c] = *(const short8*)p;
        alt.l[c] = *(const short8*)(p + nlo);
      }
    }
    const int ka = kc * 32 + quad * 8;
    const short8 Ah = (amax < 0 || ka < amax)
        ? *(const short8*)(XA + (m0 + nn) * ast + ka)
        : *(const short8*)ZS;
    #pragma unroll
    for (int c = 0; c < C; ++c) {
      Cacc[c] = MFMA_BF16(Ah, cur.h[c], Cacc[c], 0, 0, 0);
      Cacc[c] = MFMA_BF16(Ah, cur.l[c], Cacc[c], 0, 0, 0);
    }
  }
}

__global__ __launch_bounds__(256, 4) void fused_kernel(
    const int* __restrict__ fps_idx, const int* __restrict__ group_idx,
    float* __restrict__ out)
{
  __shared__ __align__(16) unsigned char LB[LDSB];
  unsigned short* XAh = (unsigned short*)(LB + OXAH);
  unsigned short* XBh = (unsigned short*)(LB + OXBH);
  unsigned short* XHh = (unsigned short*)(LB + OXHH);
  float*          EQ  = (float*)(LB + OEQ);
  float*          FS  = (float*)(LB + OFS);
  unsigned short* ZS  = (unsigned short*)(LB + OZST);

  const int t = threadIdx.x, lane = t & 63, wave = t >> 6;
  const int quad = lane >> 4, nn = lane & 15;
  const int mt = wave >> 1, ch = wave & 1;
  const int m0 = mt * 16;
  const int g = blockIdx.x;
  const int b = g >> 10, p = g & 1023;

  // ---- preload phase-1 kc0 B-fragments (covers S0/S1 latency) ----
  B4 bufs[2];
  #pragma unroll
  for (int c = 0; c < 2; ++c) {
    const unsigned short* pp = g_Wb + W1BH + (ch * 32 + c * 16 + nn) * 96 + quad * 8;
    bufs[0].h[c] = *(const short8*)pp;
    bufs[0].l[c] = *(const short8*)(pp + (W1BL - W1BH));
  }

  // ---- S0: zero stub; fps row; out0 ----
  if (t < 4) ((float*)ZS)[t] = 0.f;
  {
    const int fi = fps_idx[g];
    const float* frow = g_pts + (((long)b << 12) + fi) * 68;
    if (t < 64) {
      FS[4 + t] = frow[t];
    } else if (t < 67) {
      const int d = t - 64;
      const float v = frow[t];
      FS[d] = v;
      out[(b * 3 + d) * Pn + p] = v;
    }
  }
  __syncthreads();

  // ---- S1: gather from g_pts rows; rxyz; zero pads ----
  {
    const int s0 = t >> 3, cg = t & 7;
    const int gi = group_idx[g * Sn + s0];
    const float* prow = g_pts + (((long)b << 12) + gi) * 68;
    const int c0 = cg * 8;
    const float4 va = *(const float4*)(prow + c0);
    const float4 vb = *(const float4*)(prow + c0 + 4);
    XAh[s0 * 80 + c0 + 0] = bfh(va.x); XAh[s0 * 80 + c0 + 1] = bfh(va.y);
    XAh[s0 * 80 + c0 + 2] = bfh(va.z); XAh[s0 * 80 + c0 + 3] = bfh(va.w);
    XAh[s0 * 80 + c0 + 4] = bfh(vb.x); XAh[s0 * 80 + c0 + 5] = bfh(vb.y);
    XAh[s0 * 80 + c0 + 6] = bfh(vb.z); XAh[s0 * 80 + c0 + 7] = bfh(vb.w);
    if (cg == 0) {
      #pragma unroll
      for (int d = 0; d < 3; ++d) {
        const float r = prow[64 + d] - FS[d];
        const unsigned short hu = bfh(r);
        XAh[s0 * 80 + 64 + d] = hu;
        XHh[s0 * 144 + 128 + d] = hu;
      }
    } else if (cg == 1) {
      #pragma unroll
      for (int j = 0; j < 13; ++j) XAh[s0 * 80 + 67 + j] = 0;
    } else if (cg == 2) {
      #pragma unroll
      for (int j = 0; j < 13; ++j) XHh[s0 * 144 + 131 + j] = 0;
    }
  }
  __syncthreads();

  f32x4 C[4];

  // ===== Phase 1: X(K96) @ W1b -> h1(XBh); fps-L1 =====
  C[0] = (f32x4){0.f,0.f,0.f,0.f}; C[1] = (f32x4){0.f,0.f,0.f,0.f};
  run_phase<3, 2, 0, true, 2>(
      g_Wb + W1BH, W1BL - W1BH, 96, ch * 32, XAh, 80, 80, ZS, nn, quad, m0,
      g_Wb + W2BH, W2BL - W2BH, 64, ch * 32, bufs, C);
  {
    const int o = (t & 127) >> 1, kh = t & 1;
    float a2 = 0.f;
    if (kh == 0) {
      #pragma unroll 2
      for (int k = 0; k < 34; ++k) a2 = fmaf(FS[4 + k], g_W[W1O + k * 64 + o], a2);
    } else {
      #pragma unroll 2
      for (int k = 34; k < 64; ++k) a2 = fmaf(FS[4 + k], g_W[W1O + k * 64 + o], a2);
      #pragma unroll
      for (int d = 0; d < 3; ++d) a2 = fmaf(FS[d], g_W[W1O + (64 + d) * 64 + o], a2);
    }
    a2 += __shfl_xor(a2, 1);
    if (kh == 0) FS[68 + o] = fmaxf(a2 + g_W[B1O + o], 0.f);
  }
  #pragma unroll
  for (int c = 0; c < 2; ++c) {
    const int col = ch * 32 + c * 16 + nn;
    #pragma unroll
    for (int r = 0; r < 4; ++r) {
      const int row = m0 + quad * 4 + r;
      XBh[row * 64 + col] = bfh(fmaxf(C[c][r] + g_W[B1O + col], 0.f));
    }
  }
  __syncthreads();

  // ===== Phase 2: h1(K64) @ W2b -> h2(XAh cols0..63); fps-L2 =====
  C[0] = (f32x4){0.f,0.f,0.f,0.f}; C[1] = (f32x4){0.f,0.f,0.f,0.f};
  run_phase<2, 2, 1, true, 4>(
      g_Wb + W2BH, W2BL - W2BH, 64, ch * 32, XBh, 64, -1, ZS, nn, quad, m0,
      g_Wb + W3BH, W3BL - W3BH, 64, ch * 64, bufs, C);
  {
    const int o = (t & 127) >> 1, kh = t & 1;
    float a2 = 0.f;
    #pragma unroll 2
    for (int k = kh * 32; k < kh * 32 + 32; ++k)
      a2 = fmaf(FS[68 + k], g_W[W2O + k * 64 + o], a2);
    a2 += __shfl_xor(a2, 1);
    if (kh == 0) FS[4 + o] = fmaxf(a2 + g_W[B2O + o], 0.f);
  }
  #pragma unroll
  for (int c = 0; c < 2; ++c) {
    const int col = ch * 32 + c * 16 + nn;
    #pragma unroll
    for (int r = 0; r < 4; ++r) {
      const int row = m0 + quad * 4 + r;
      XAh[row * 80 + col] = bfh(fmaxf(C[c][r] + g_W[B2O + col], 0.f));
    }
  }
  __syncthreads();

  // ===== Phase 3: h2(K64) @ W3b -> h3(XHh cols0..127); fps-L3 =====
  #pragma unroll
  for (int i = 0; i < 4; ++i) C[i] = (f32x4){0.f,0.f,0.f,0.f};
  run_phase<2, 4, 1, true, 4>(
      g_Wb + W3BH, W3BL - W3BH, 64, ch * 64, XAh, 80, -1, ZS, nn, quad, m0,
      g_Wb + ABH, ABL - ABH, 160, ch * 64, bufs, C);
  {
    const int o = t & 127;
    float a2 = 0.f;
    #pragma unroll 4
    for (int k = 0; k < 64; ++k)
      a2 = fmaf(FS[4 + k], g_W[W3O + k * 128 + o], a2);
    FS[68 + o] = fmaxf(a2 + g_W[B3O + o], 0.f);
  }
  #pragma unroll
  for (int c = 0; c < 4; ++c) {
    const int col = ch * 64 + c * 16 + nn;
    #pragma unroll
    for (int r = 0; r < 4; ++r) {
      const int row = m0 + quad * 4 + r;
      XHh[row * 144 + col] = bfh(fmaxf(C[c][r] + g_W[B3O + col], 0.f));
    }
  }
  __syncthreads();

  // ===== ebias (fp32); overwrites F3 =====
  {
    const int o = t & 127;
    const float* ap = g_W + AO + (o >> 6) * 8448 + (o & 63);
    float a2 = 0.f;
    #pragma unroll 4
    for (int k = 0; k < 128; ++k) a2 = fmaf(FS[68 + k], ap[k * 64], a2);
    #pragma unroll
    for (int d = 0; d < 3; ++d) a2 = fmaf(FS[d], ap[(128 + d) * 64], a2);
    __syncthreads();
    FS[68 + o] = a2;
    __syncthreads();
  }

  // ===== Phase 5: [h3|rxyz](K160) @ Ab -> scores -> EQ =====
  #pragma unroll
  for (int i = 0; i < 4; ++i) C[i] = (f32x4){0.f,0.f,0.f,0.f};
  run_phase<5, 4, 1, false, 0>(
      g_Wb + ABH, ABL - ABH, 160, ch * 64, XHh, 144, 144, ZS, nn, quad, m0,
      (const unsigned short*)nullptr, 0, 0, 0, bufs, C);
  #pragma unroll
  for (int c = 0; c < 4; ++c) {
    const int col = ch * 64 + c * 16 + nn;
    #pragma unroll
    for (int r = 0; r < 4; ++r) {
      const int row = m0 + quad * 4 + r;
      float e = FS[68 + col] - C[c][r];
      EQ[row * 129 + col] = (e > 0.f) ? e : ALPHAn * e;
    }
  }
  __syncthreads();

  // ===== softmax + pooled sum -> g_tmp (dense) =====
  if (t < 128) {
    const int c = t;
    const float* ec = EQ + c;
    float mx = -3.4e38f;
    #pragma unroll 4
    for (int si = 0; si < 32; ++si) mx = fmaxf(mx, ec[si * 129]);
    float den = 0.f, pool = 0.f;
    #pragma unroll 4
    for (int si = 0; si < 32; ++si) {
      const float w = __expf(ec[si * 129] - mx);
      den += w;
      pool = fmaf(w, bf2f(XHh[si * 144 + c]), pool);
    }
    g_tmp[(long)g * 128 + c] = pool / den;
  }
}

extern "C" void kernel_launch(void* const* d_in, const int* in_sizes, int n_in,
                              void* d_out, int out_size, void* d_ws, size_t ws_size,
                              hipStream_t stream) {
  const float* xyz       = (const float*)d_in[0];
  const float* points    = (const float*)d_in[1];
  const int*   fps_idx   = (const int*)d_in[2];
  const int*   group_idx = (const int*)d_in[3];

  const int prep_blocks = 1024 + (WSF + NPAIR + 255) / 256;
  prep_kernel<<<prep_blocks, 256, 0, stream>>>(
      xyz, points,
      (const float*)d_in[4],  (const float*)d_in[5],
      (const float*)d_in[6],  (const float*)d_in[7],
      (const float*)d_in[8],  (const float*)d_in[9],
      (const float*)d_in[10], (const float*)d_in[11],
      (const float*)d_in[12], (const float*)d_in[13],
      (const float*)d_in[14], (const float*)d_in[15],
      (const float*)d_in[16], (const float*)d_in[17],
      (const float*)d_in[18], (const float*)d_in[19],
      (const float*)d_in[20], (const float*)d_in[21],
      (const float*)d_in[22]);

  fused_kernel<<<Bn * Pn, 256, 0, stream>>>(fps_idx, group_idx, (float*)d_out);

  transpose_out<<<Bn * 16, 256, 0, stream>>>((float*)d_out);
}

// Round 14
// 563.626 us; speedup vs baseline: 1.5189x; 1.3685x over previous
//
#include <hip/hip_runtime.h>
#include <hip/hip_bf16.h>

#define Bn 16
#define Nn 4096
#define Pn 1024
#define Sn 32
#define Cn 64
#define EPSn 1e-5f
#define ALPHAn 0.2f

// ---- fp32 weight table (fps scalar path) ----
#define W1O 0       // [68][64] k-order [feat64|xyz3|pad]
#define W2O 4352    // [64][64]
#define W3O 8448    // [64][128]
#define AO  16640   // two col-halves [132][64]; k-order [h3|xyz|pad]
#define B1O 33536
#define B2O 33600
#define B3O 33664
#define WSF 33792
__device__ __align__(16) float g_W[WSF];

// ---- FRAGMENT-MAJOR split-bf16 weights (R14): g_Wf[frag][lane][8] u16.
// A wave's B-fragment load = base + lane*16B -> fully coalesced 1KB request
// (R13 analysis: row-scattered fragment gathers cost ~16-32 TA cycles each;
// this layout makes them ~2-4). frag order:
//   phase1 [0,24):  ((ch*3+kc)*2+c)*2+plane   (c<2)
//   phase2 [24,40): ((ch*2+kc)*2+c)*2+plane   (c<2)
//   phase3 [40,72): ((ch*2+kc)*4+c)*2+plane   (c<4)
//   phase5 [72,152):((ch*5+kc)*4+c)*2+plane   (c<4)
// element: n = ch*(16*C) + c*16 + nn,  k = kc*32 + quad*8 + j
#define F1F 0
#define F2F 24
#define F3F 40
#define F5F 72
#define NFRAG 152
#define WFU (NFRAG * 512)
__device__ __align__(16) unsigned short g_Wf[WFU];

// ---- row-major point store [b][n][68]; dense out1 staging ----
__device__ __align__(16) float g_pts[Bn * Nn * 68];
__device__ __align__(16) float g_tmp[Bn * Pn * 128];

typedef __attribute__((ext_vector_type(8))) short short8;
typedef __attribute__((ext_vector_type(4))) float f32x4;

__device__ __forceinline__ void split2(float v, unsigned short& hu, unsigned short& lu) {
  __hip_bfloat16 h = __float2bfloat16(v);
  float hv = __bfloat162float(h);
  __hip_bfloat16 l = __float2bfloat16(v - hv);
  hu = *(unsigned short*)&h;
  lu = *(unsigned short*)&l;
}
__device__ __forceinline__ unsigned short bfh(float v) {
  __hip_bfloat16 h = __float2bfloat16(v);
  return *(unsigned short*)&h;
}
__device__ __forceinline__ float bf2f(unsigned short u) {
  __hip_bfloat16 h = *(__hip_bfloat16*)&u;
  return __bfloat162float(h);
}

// Merged prep: blocks [0,1024) transpose points->g_pts; rest fold weights.
__global__ __launch_bounds__(256) void prep_kernel(
    const float* __restrict__ xyz, const float* __restrict__ points,
    const float* __restrict__ w1, const float* __restrict__ b1,
    const float* __restrict__ g1, const float* __restrict__ bt1,
    const float* __restrict__ m1, const float* __restrict__ v1,
    const float* __restrict__ w2, const float* __restrict__ b2,
    const float* __restrict__ g2, const float* __restrict__ bt2,
    const float* __restrict__ m2, const float* __restrict__ v2,
    const float* __restrict__ w3, const float* __restrict__ b3,
    const float* __restrict__ g3, const float* __restrict__ bt3,
    const float* __restrict__ m3, const float* __restrict__ v3,
    const float* __restrict__ a)
{
  if (blockIdx.x < 1024) {   // transpose tile
    __shared__ float T[68 * 65];
    const int t = threadIdx.x;
    const int b = blockIdx.x >> 6, n0 = (blockIdx.x & 63) << 6;
    const int nn = t & 63, cgrp = t >> 6;
    #pragma unroll
    for (int k = 0; k < 16; ++k) {
      const int c = cgrp * 16 + k;
      T[c * 65 + nn] = points[(b * Cn + c) * Nn + n0 + nn];
    }
    if (cgrp == 0) {
      #pragma unroll
      for (int d = 0; d < 3; ++d)
        T[(64 + d) * 65 + nn] = xyz[(b * 3 + d) * Nn + n0 + nn];
      T[67 * 65 + nn] = 0.f;
    }
    __syncthreads();
    const int row = t >> 2, j0 = (t & 3) * 17;
    float* dst = g_pts + (((long)b << 12) + n0 + row) * 68 + j0;
    #pragma unroll
    for (int j = 0; j < 17; ++j) dst[j] = T[(j0 + j) * 65 + row];
    return;
  }
  const int idx = (blockIdx.x - 1024) * blockDim.x + threadIdx.x;
  if (idx < WSF) {
    float val;
    if (idx < W2O) {
      const int k = idx >> 6, o = idx & 63;
      const float sc = g1[o] * rsqrtf(v1[o] + EPSn);
      val = (k < 64) ? w1[o * 67 + 3 + k] * sc
          : (k < 67) ? w1[o * 67 + (k - 64)] * sc : 0.f;
    } else if (idx < W3O) {
      const int r = idx - W2O, k = r >> 6, o = r & 63;
      val = w2[o * 64 + k] * (g2[o] * rsqrtf(v2[o] + EPSn));
    } else if (idx < AO) {
      const int r = idx - W3O, k = r >> 7, o = r & 127;
      val = w3[o * 64 + k] * (g3[o] * rsqrtf(v3[o] + EPSn));
    } else if (idx < B1O) {
      int r = idx - AO;
      const int half = r / 8448; r -= half * 8448;
      const int k = r >> 6, o = half * 64 + (r & 63);
      val = (k < 128) ? a[(3 + k) * 128 + o]
          : (k < 131) ? a[(k - 128) * 128 + o] : 0.f;
    } else if (idx < B2O) {
      const int o = idx - B1O;
      val = (b1[o] - m1[o]) * (g1[o] * rsqrtf(v1[o] + EPSn)) + bt1[o];
    } else if (idx < B3O) {
      const int o = idx - B2O;
      val = (b2[o] - m2[o]) * (g2[o] * rsqrtf(v2[o] + EPSn)) + bt2[o];
    } else {
      const int o = idx - B3O;
      val = (b3[o] - m3[o]) * (g3[o] * rsqrtf(v3[o] + EPSn)) + bt3[o];
    }
    g_W[idx] = val;
  } else if (idx < WSF + WFU) {
    const int i = idx - WSF;
    const int frag = i >> 9, r = i & 511;
    const int lane = r >> 3, j = r & 7;
    const int quad = lane >> 4, nn = lane & 15;
    int plane, n, k;
    float w;
    if (frag < F2F) {                 // phase1: W1, C=2
      const int f = frag;
      plane = f & 1;
      const int c = (f >> 1) & 1, kcch = f >> 2, kc = kcch % 3, ch = kcch / 3;
      n = ch * 32 + c * 16 + nn; k = kc * 32 + quad * 8 + j;
      const float s = g1[n] * rsqrtf(v1[n] + EPSn);
      w = (k < 64) ? w1[n * 67 + 3 + k] * s
        : (k < 67) ? w1[n * 67 + (k - 64)] * s : 0.f;
    } else if (frag < F3F) {          // phase2: W2, C=2
      const int f = frag - F2F;
      plane = f & 1;
      const int c = (f >> 1) & 1, kc = (f >> 2) & 1, ch = f >> 3;
      n = ch * 32 + c * 16 + nn; k = kc * 32 + quad * 8 + j;
      w = w2[n * 64 + k] * (g2[n] * rsqrtf(v2[n] + EPSn));
    } else if (frag < F5F) {          // phase3: W3, C=4
      const int f = frag - F3F;
      plane = f & 1;
      const int c = (f >> 1) & 3, kc = (f >> 3) & 1, ch = f >> 4;
      n = ch * 64 + c * 16 + nn; k = kc * 32 + quad * 8 + j;
      w = w3[n * 64 + k] * (g3[n] * rsqrtf(v3[n] + EPSn));
    } else {                          // phase5: A, C=4, KC=5
      const int f = frag - F5F;
      plane = f & 1;
      const int c = (f >> 1) & 3, kcch = f >> 3, kc = kcch % 5, ch = kcch / 5;
      n = ch * 64 + c * 16 + nn; k = kc * 32 + quad * 8 + j;
      w = (k < 128) ? a[(3 + k) * 128 + n]
        : (k < 131) ? a[(k - 128) * 128 + n] : 0.f;
    }
    unsigned short hu, lu; split2(w, hu, lu);
    g_Wf[i] = plane ? lu : hu;
  }
}

// Epilogue: g_tmp[b][p][128] -> out1[b][c][p]
__global__ __launch_bounds__(256) void transpose_out(float* __restrict__ out)
{
  __shared__ float T[64 * 129];
  const int t = threadIdx.x;
  const int b = blockIdx.x >> 4, p0 = (blockIdx.x & 15) << 6;
  const int c = t & 127, ph = t >> 7;
  #pragma unroll
  for (int pp = 0; pp < 32; ++pp) {
    const int pi = ph * 32 + pp;
    T[pi * 129 + c] = g_tmp[(((long)b << 10) + p0 + pi) * 128 + c];
  }
  __syncthreads();
  const int pn = t & 63, cg = t >> 6;
  #pragma unroll
  for (int k = 0; k < 32; ++k) {
    const int cc = cg * 32 + k;
    out[Bn * 3 * Pn + ((b << 7) + cc) * Pn + p0 + pn] = T[pn * 129 + cc];
  }
}

// ---- LDS (bytes), 1 group/block: 40864 B -> 4 blocks/CU ----
#define OXAH 0
#define OXBH 10240
#define OXHH 14336
#define OEQ  23552
#define OFS  40064
#define OZST 40848
#define LDSB 40864

#define MFMA_BF16 __builtin_amdgcn_mfma_f32_16x16x32_bf16

__global__ __launch_bounds__(256, 4) void fused_kernel(
    const int* __restrict__ fps_idx, const int* __restrict__ group_idx,
    float* __restrict__ out)
{
  __shared__ __align__(16) unsigned char LB[LDSB];
  unsigned short* XAh = (unsigned short*)(LB + OXAH);
  unsigned short* XBh = (unsigned short*)(LB + OXBH);
  unsigned short* XHh = (unsigned short*)(LB + OXHH);
  float*          EQ  = (float*)(LB + OEQ);
  float*          FS  = (float*)(LB + OFS);
  unsigned short* ZS  = (unsigned short*)(LB + OZST);

  const int t = threadIdx.x, lane = t & 63, wave = t >> 6;
  const int quad = lane >> 4, nn = lane & 15;
  const int mt = wave >> 1, ch = wave & 1;
  const int m0 = mt * 16;
  const int g = blockIdx.x;
  const int b = g >> 10, p = g & 1023;

  // ---- S0: zero stub; fps row; out0 ----
  if (t < 4) ((float*)ZS)[t] = 0.f;
  {
    const int fi = fps_idx[g];
    const float* frow = g_pts + (((long)b << 12) + fi) * 68;
    if (t < 64) {
      FS[4 + t] = frow[t];
    } else if (t < 67) {
      const int d = t - 64;
      const float v = frow[t];
      FS[d] = v;
      out[(b * 3 + d) * Pn + p] = v;
    }
  }
  __syncthreads();

  // ---- S1: gather from g_pts rows; rxyz; zero pads ----
  {
    const int s0 = t >> 3, cg = t & 7;
    const int gi = group_idx[g * Sn + s0];
    const float* prow = g_pts + (((long)b << 12) + gi) * 68;
    const int c0 = cg * 8;
    const float4 va = *(const float4*)(prow + c0);
    const float4 vb = *(const float4*)(prow + c0 + 4);
    XAh[s0 * 80 + c0 + 0] = bfh(va.x); XAh[s0 * 80 + c0 + 1] = bfh(va.y);
    XAh[s0 * 80 + c0 + 2] = bfh(va.z); XAh[s0 * 80 + c0 + 3] = bfh(va.w);
    XAh[s0 * 80 + c0 + 4] = bfh(vb.x); XAh[s0 * 80 + c0 + 5] = bfh(vb.y);
    XAh[s0 * 80 + c0 + 6] = bfh(vb.z); XAh[s0 * 80 + c0 + 7] = bfh(vb.w);
    if (cg == 0) {
      #pragma unroll
      for (int d = 0; d < 3; ++d) {
        const float r = prow[64 + d] - FS[d];
        const unsigned short hu = bfh(r);
        XAh[s0 * 80 + 64 + d] = hu;
        XHh[s0 * 144 + 128 + d] = hu;
      }
    } else if (cg == 1) {
      #pragma unroll
      for (int j = 0; j < 13; ++j) XAh[s0 * 80 + 67 + j] = 0;
    } else if (cg == 2) {
      #pragma unroll
      for (int j = 0; j < 13; ++j) XHh[s0 * 144 + 131 + j] = 0;
    }
  }
  __syncthreads();

  f32x4 C[4];

  // ===== Phase 1: X(K96) @ W1f -> h1(XBh); fps-L1 =====
  C[0] = (f32x4){0.f,0.f,0.f,0.f}; C[1] = (f32x4){0.f,0.f,0.f,0.f};
  #pragma unroll
  for (int kc = 0; kc < 3; ++kc) {
    const int ka = kc * 32 + quad * 8;
    const short8 Ah = (ka < 80) ? *(const short8*)(XAh + (m0 + nn) * 80 + ka)
                                : *(const short8*)ZS;
    #pragma unroll
    for (int c = 0; c < 2; ++c) {
      const unsigned short* pf = g_Wf + (((ch * 3 + kc) * 2 + c) * 2) * 512 + lane * 8;
      C[c] = MFMA_BF16(Ah, *(const short8*)pf, C[c], 0, 0, 0);
      C[c] = MFMA_BF16(Ah, *(const short8*)(pf + 512), C[c], 0, 0, 0);
    }
  }
  {
    const int o = (t & 127) >> 1, kh = t & 1;
    float a2 = 0.f;
    if (kh == 0) {
      #pragma unroll 2
      for (int k = 0; k < 34; ++k) a2 = fmaf(FS[4 + k], g_W[W1O + k * 64 + o], a2);
    } else {
      #pragma unroll 2
      for (int k = 34; k < 64; ++k) a2 = fmaf(FS[4 + k], g_W[W1O + k * 64 + o], a2);
      #pragma unroll
      for (int d = 0; d < 3; ++d) a2 = fmaf(FS[d], g_W[W1O + (64 + d) * 64 + o], a2);
    }
    a2 += __shfl_xor(a2, 1);
    if (kh == 0) FS[68 + o] = fmaxf(a2 + g_W[B1O + o], 0.f);
  }
  #pragma unroll
  for (int c = 0; c < 2; ++c) {
    const int col = ch * 32 + c * 16 + nn;
    #pragma unroll
    for (int r = 0; r < 4; ++r) {
      const int row = m0 + quad * 4 + r;
      XBh[row * 64 + col] = bfh(fmaxf(C[c][r] + g_W[B1O + col], 0.f));
    }
  }
  __syncthreads();

  // ===== Phase 2: h1(K64) @ W2f -> h2(XAh cols0..63); fps-L2 =====
  C[0] = (f32x4){0.f,0.f,0.f,0.f}; C[1] = (f32x4){0.f,0.f,0.f,0.f};
  #pragma unroll
  for (int kc = 0; kc < 2; ++kc) {
    const int ka = kc * 32 + quad * 8;
    const short8 Ah = *(const short8*)(XBh + (m0 + nn) * 64 + ka);
    #pragma unroll
    for (int c = 0; c < 2; ++c) {
      const unsigned short* pf = g_Wf + (F2F + ((ch * 2 + kc) * 2 + c) * 2) * 512 + lane * 8;
      C[c] = MFMA_BF16(Ah, *(const short8*)pf, C[c], 0, 0, 0);
      C[c] = MFMA_BF16(Ah, *(const short8*)(pf + 512), C[c], 0, 0, 0);
    }
  }
  {
    const int o = (t & 127) >> 1, kh = t & 1;
    float a2 = 0.f;
    #pragma unroll 2
    for (int k = kh * 32; k < kh * 32 + 32; ++k)
      a2 = fmaf(FS[68 + k], g_W[W2O + k * 64 + o], a2);
    a2 += __shfl_xor(a2, 1);
    if (kh == 0) FS[4 + o] = fmaxf(a2 + g_W[B2O + o], 0.f);
  }
  #pragma unroll
  for (int c = 0; c < 2; ++c) {
    const int col = ch * 32 + c * 16 + nn;
    #pragma unroll
    for (int r = 0; r < 4; ++r) {
      const int row = m0 + quad * 4 + r;
      XAh[row * 80 + col] = bfh(fmaxf(C[c][r] + g_W[B2O + col], 0.f));
    }
  }
  __syncthreads();

  // ===== Phase 3: h2(K64) @ W3f -> h3(XHh cols0..127); fps-L3 =====
  #pragma unroll
  for (int i = 0; i < 4; ++i) C[i] = (f32x4){0.f,0.f,0.f,0.f};
  #pragma unroll
  for (int kc = 0; kc < 2; ++kc) {
    const int ka = kc * 32 + quad * 8;
    const short8 Ah = *(const short8*)(XAh + (m0 + nn) * 80 + ka);
    #pragma unroll
    for (int c = 0; c < 4; ++c) {
      const unsigned short* pf = g_Wf + (F3F + ((ch * 2 + kc) * 4 + c) * 2) * 512 + lane * 8;
      C[c] = MFMA_BF16(Ah, *(const short8*)pf, C[c], 0, 0, 0);
      C[c] = MFMA_BF16(Ah, *(const short8*)(pf + 512), C[c], 0, 0, 0);
    }
  }
  {
    const int o = t & 127;
    float a2 = 0.f;
    #pragma unroll 4
    for (int k = 0; k < 64; ++k)
      a2 = fmaf(FS[4 + k], g_W[W3O + k * 128 + o], a2);
    FS[68 + o] = fmaxf(a2 + g_W[B3O + o], 0.f);
  }
  #pragma unroll
  for (int c = 0; c < 4; ++c) {
    const int col = ch * 64 + c * 16 + nn;
    #pragma unroll
    for (int r = 0; r < 4; ++r) {
      const int row = m0 + quad * 4 + r;
      XHh[row * 144 + col] = bfh(fmaxf(C[c][r] + g_W[B3O + col], 0.f));
    }
  }
  __syncthreads();

  // ===== ebias (fp32); overwrites F3 =====
  {
    const int o = t & 127;
    const float* ap = g_W + AO + (o >> 6) * 8448 + (o & 63);
    float a2 = 0.f;
    #pragma unroll 4
    for (int k = 0; k < 128; ++k) a2 = fmaf(FS[68 + k], ap[k * 64], a2);
    #pragma unroll
    for (int d = 0; d < 3; ++d) a2 = fmaf(FS[d], ap[(128 + d) * 64], a2);
    __syncthreads();
    FS[68 + o] = a2;
    __syncthreads();
  }

  // ===== Phase 5: [h3|rxyz](K160) @ Af -> scores -> EQ =====
  #pragma unroll
  for (int i = 0; i < 4; ++i) C[i] = (f32x4){0.f,0.f,0.f,0.f};
  #pragma unroll
  for (int kc = 0; kc < 5; ++kc) {
    const int ka = kc * 32 + quad * 8;
    const short8 Ah = (ka < 144) ? *(const short8*)(XHh + (m0 + nn) * 144 + ka)
                                 : *(const short8*)ZS;
    #pragma unroll
    for (int c = 0; c < 4; ++c) {
      const unsigned short* pf = g_Wf + (F5F + ((ch * 5 + kc) * 4 + c) * 2) * 512 + lane * 8;
      C[c] = MFMA_BF16(Ah, *(const short8*)pf, C[c], 0, 0, 0);
      C[c] = MFMA_BF16(Ah, *(const short8*)(pf + 512), C[c], 0, 0, 0);
    }
  }
  #pragma unroll
  for (int c = 0; c < 4; ++c) {
    const int col = ch * 64 + c * 16 + nn;
    #pragma unroll
    for (int r = 0; r < 4; ++r) {
      const int row = m0 + quad * 4 + r;
      float e = FS[68 + col] - C[c][r];
      EQ[row * 129 + col] = (e > 0.f) ? e : ALPHAn * e;
    }
  }
  __syncthreads();

  // ===== softmax + pooled sum -> g_tmp (dense) =====
  if (t < 128) {
    const int c = t;
    const float* ec = EQ + c;
    float mx = -3.4e38f;
    #pragma unroll 4
    for (int si = 0; si < 32; ++si) mx = fmaxf(mx, ec[si * 129]);
    float den = 0.f, pool = 0.f;
    #pragma unroll 4
    for (int si = 0; si < 32; ++si) {
      const float w = __expf(ec[si * 129] - mx);
      den += w;
      pool = fmaf(w, bf2f(XHh[si * 144 + c]), pool);
    }
    g_tmp[(long)g * 128 + c] = pool / den;
  }
}

extern "C" void kernel_launch(void* const* d_in, const int* in_sizes, int n_in,
                              void* d_out, int out_size, void* d_ws, size_t ws_size,
                              hipStream_t stream) {
  const float* xyz       = (const float*)d_in[0];
  const float* points    = (const float*)d_in[1];
  const int*   fps_idx   = (const int*)d_in[2];
  const int*   group_idx = (const int*)d_in[3];

  const int prep_blocks = 1024 + (WSF + WFU + 255) / 256;
  prep_kernel<<<prep_blocks, 256, 0, stream>>>(
      xyz, points,
      (const float*)d_in[4],  (const float*)d_in[5],
      (const float*)d_in[6],  (const float*)d_in[7],
      (const float*)d_in[8],  (const float*)d_in[9],
      (const float*)d_in[10], (const float*)d_in[11],
      (const float*)d_in[12], (const float*)d_in[13],
      (const float*)d_in[14], (const float*)d_in[15],
      (const float*)d_in[16], (const float*)d_in[17],
      (const float*)d_in[18], (const float*)d_in[19],
      (const float*)d_in[20], (const float*)d_in[21],
      (const float*)d_in[22]);

  fused_kernel<<<Bn * Pn, 256, 0, stream>>>(fps_idx, group_idx, (float*)d_out);

  transpose_out<<<Bn * 16, 256, 0, stream>>>((float*)d_out);
}